// Round 16
// baseline (223.206 us; speedup 1.0000x reference)
//
#include <hip/hip_runtime.h>
#include <stdint.h>

typedef unsigned short u16;
typedef u16 u16x4 __attribute__((ext_vector_type(4)));
typedef unsigned int u32x4 __attribute__((ext_vector_type(4)));
typedef float f32x4 __attribute__((ext_vector_type(4)));
typedef float f32x16 __attribute__((ext_vector_type(16)));
typedef __bf16 bf16x8 __attribute__((ext_vector_type(8)));

#define DEVI __device__ __forceinline__

DEVI u16 f2bf(float f) {
  uint32_t u = __builtin_bit_cast(uint32_t, f);
  u = (u + 0x7FFFu + ((u >> 16) & 1u)) >> 16;
  return (u16)u;
}
DEVI float bf2f(u16 h) {
  uint32_t u = ((uint32_t)h) << 16;
  return __builtin_bit_cast(float, u);
}
DEVI f32x4 mfma16(u32x4 a, u32x4 b, f32x4 c) {
  return __builtin_amdgcn_mfma_f32_16x16x32_bf16(
      __builtin_bit_cast(bf16x8, a), __builtin_bit_cast(bf16x8, b), c, 0, 0, 0);
}
DEVI f32x16 mfma32(u32x4 a, u32x4 b, f32x16 c) {
  return __builtin_amdgcn_mfma_f32_32x32x16_bf16(
      __builtin_bit_cast(bf16x8, a), __builtin_bit_cast(bf16x8, b), c, 0, 0, 0);
}
DEVI uint32_t cvtpk(float lo, float hi) {
  uint32_t w;
  asm("v_cvt_pk_bf16_f32 %0, %1, %2" : "=v"(w) : "v"(lo), "v"(hi));
  return w;
}
DEVI void plswap(uint32_t& a, uint32_t& b) {
  asm("v_permlane32_swap_b32 %0, %1" : "+v"(a), "+v"(b));
}
DEVI float xmax2(float v) {
  uint32_t a = __builtin_bit_cast(uint32_t, v), b = a;
  plswap(a, b);
  return fmaxf(__builtin_bit_cast(float, a), __builtin_bit_cast(float, b));
}
DEVI float ex2(float x) { return __builtin_amdgcn_exp2f(x); }

#define AS1 __attribute__((address_space(1)))
#define AS3 __attribute__((address_space(3)))
DEVI void gload16(const void* g, void* l) {
  __builtin_amdgcn_global_load_lds((AS1 void*)(uintptr_t)g,
                                   (AS3 void*)(uint32_t)(uintptr_t)l, 16, 0, 0);
}

DEVI float wred(float v) {
#pragma unroll
  for (int m = 1; m < 64; m <<= 1) v += __shfl_xor(v, m);
  return v;
}

// ---------------- merged prep (5 weight transposes) + LN1 in ONE launch -------------
__global__ __launch_bounds__(256) void k_prep_ln1(
    const float* __restrict__ Wq, const float* __restrict__ Wk,
    const float* __restrict__ Wv, const float* __restrict__ W1,
    const float* __restrict__ W2, const float* __restrict__ x,
    const float* __restrict__ gam, const float* __restrict__ bet,
    u16* __restrict__ wqkv_t, u16* __restrict__ w1t, u16* __restrict__ w2t,
    u16* __restrict__ xn_res) {
  __shared__ float tile[64][65];
  int bid = blockIdx.x, tid = threadIdx.x;
  if (bid < 448) {
    const float* W;
    u16* Wt;
    int Kr, Nc, n0, k0;
    if (bid < 192) {
      int w = bid / 64, t = bid & 63;
      W = (w == 0) ? Wq : (w == 1) ? Wk : Wv;
      Wt = wqkv_t + (size_t)w * 512 * 512;
      Kr = 512; Nc = 512; n0 = (t & 7) * 64; k0 = (t >> 3) * 64;
    } else if (bid < 320) {
      int t = bid - 192;
      W = W1; Wt = w1t;
      Kr = 512; Nc = 1024; n0 = (t & 15) * 64; k0 = (t >> 4) * 64;
    } else {
      int t = bid - 320;
      W = W2; Wt = w2t;
      Kr = 1024; Nc = 512; n0 = (t & 7) * 64; k0 = (t >> 3) * 64;
    }
#pragma unroll
    for (int i = 0; i < 16; i++) {
      int idx = i * 256 + tid;
      int r = idx >> 6, cc = idx & 63;
      tile[r][cc] = W[(size_t)(k0 + r) * Nc + n0 + cc];
    }
    __syncthreads();
#pragma unroll
    for (int i = 0; i < 16; i++) {
      int idx = i * 256 + tid;
      int r = idx >> 6, cc = idx & 63;
      Wt[(size_t)(n0 + r) * Kr + k0 + cc] = f2bf(tile[cc][r]);
    }
  } else {
    int wid = tid >> 6, lane = tid & 63;
    int row = (bid - 448) * 4 + wid;
    const float* xr = x + (size_t)row * 512 + lane * 8;
    f32x4 v0 = *(const f32x4*)xr;
    f32x4 v1 = *(const f32x4*)(xr + 4);
    float s = 0.f, ss = 0.f;
#pragma unroll
    for (int j = 0; j < 4; j++) {
      s += v0[j] + v1[j];
      ss += v0[j] * v0[j] + v1[j] * v1[j];
    }
    s = wred(s);
    ss = wred(ss);
    float mean = s * (1.0f / 512.0f);
    float var = ss * (1.0f / 512.0f) - mean * mean;
    float rstd = rsqrtf(var + 1e-5f);
    const float* gp = gam + lane * 8;
    const float* bp = bet + lane * 8;
    f32x4 ga = *(const f32x4*)gp, gb = *(const f32x4*)(gp + 4);
    f32x4 ba = *(const f32x4*)bp, bb = *(const f32x4*)(bp + 4);
    u16x4 o0, o1;
#pragma unroll
    for (int j = 0; j < 4; j++) {
      o0[j] = f2bf((v0[j] - mean) * rstd * ga[j] + ba[j]);
      o1[j] = f2bf((v1[j] - mean) * rstd * gb[j] + bb[j]);
    }
    u16* pr = xn_res + (size_t)row * 512 + lane * 8;
    *(u16x4*)pr = o0;
    *(u16x4*)(pr + 4) = o1;
  }
}

// ---------------- LN2 ----------------
__global__ __launch_bounds__(256) void k_ln2(const u16* __restrict__ xn,
                                             const u16* __restrict__ ao,
                                             const float* __restrict__ gam,
                                             const float* __restrict__ bet,
                                             u16* __restrict__ xt) {
  int tid = threadIdx.x, wid = tid >> 6, lane = tid & 63;
  int row = blockIdx.x * 4 + wid;
  size_t base = (size_t)row * 512 + lane * 8;
  u16x4 a0 = *(const u16x4*)&xn[base], a1 = *(const u16x4*)&xn[base + 4];
  u16x4 c0 = *(const u16x4*)&ao[base], c1 = *(const u16x4*)&ao[base + 4];
  float v[8];
#pragma unroll
  for (int j = 0; j < 4; j++) {
    v[j] = bf2f(a0[j]) + bf2f(c0[j]);
    v[4 + j] = bf2f(a1[j]) + bf2f(c1[j]);
  }
  float s = 0.f, ss = 0.f;
#pragma unroll
  for (int j = 0; j < 8; j++) {
    s += v[j];
    ss += v[j] * v[j];
  }
  s = wred(s);
  ss = wred(ss);
  float mean = s * (1.0f / 512.0f);
  float var = ss * (1.0f / 512.0f) - mean * mean;
  float rstd = rsqrtf(var + 1e-5f);
  const float* gp = gam + lane * 8;
  const float* bp = bet + lane * 8;
  u16x4 o0, o1;
#pragma unroll
  for (int j = 0; j < 4; j++) {
    o0[j] = f2bf((v[j] - mean) * rstd * gp[j] + bp[j]);
    o1[j] = f2bf((v[4 + j] - mean) * rstd * gp[4 + j] + bp[4 + j]);
  }
  u16* pr = xt + base;
  *(u16x4*)pr = o0;
  *(u16x4*)(pr + 4) = o1;
}

// ---------------- GEMM C = A * B^T, BM x 128 tile, BK=64, 32x32 MFMA ----------------
// BM=128: 32KB LDS -> launch_bounds(256,5) = 5 blocks/CU (160KB LDS exactly,
// VGPR cap ~96 vs ~60 used). BM=64: 24.5KB -> (256,6) = 6 blocks/CU.
template <int EPI, int BM, int NB>
__global__ __launch_bounds__(256, BM == 64 ? 6 : 5) void k_gemm(
    const u16* __restrict__ A, const u16* __restrict__ B, int K, int nwg8,
    const float* __restrict__ b0, const float* __restrict__ b1,
    const float* __restrict__ b2, u16* __restrict__ o0, u16* __restrict__ o1,
    u16* __restrict__ o2, u16* __restrict__ qt, u16* __restrict__ kt,
    const u16* __restrict__ resid, float* __restrict__ outf) {
  constexpr int MI = BM / 64;
  __shared__ __align__(16) u16 As[BM * 64];
  __shared__ __align__(16) u16 Bs[128 * 64];
  const int tid = threadIdx.x;
  const int wid = tid >> 6, lane = tid & 63;
  const int r31 = lane & 31, hi = lane >> 5;
  const int bid = blockIdx.x;
  const int oid = (bid & 7) * nwg8 + (bid >> 3);
  const int m0 = (oid / NB) * BM, n0 = (oid % NB) * 128;
  const int wr = (wid >> 1) * (BM / 2), wc = (wid & 1) * 64;
  const int srow = tid >> 3, scb = tid & 7;

  f32x16 acc[MI][2];
#pragma unroll
  for (int i = 0; i < MI; i++)
#pragma unroll
    for (int j = 0; j < 2; j++)
#pragma unroll
      for (int e = 0; e < 16; e++) acc[i][j][e] = 0.f;

  auto stage = [&](int k0) {
#pragma unroll
    for (int i = 0; i < BM / 32; i++) {
      int row = i * 32 + srow;
      int col = ((scb ^ (row & 7)) << 3);
      const u16* asrc;
      if constexpr (EPI == 0) {
        int m = m0 + row;  // m = b*1024+a; source row = token a*16+b
        asrc = A + ((size_t)(((m & 1023) << 4) | (m >> 10))) * K + k0 + col;
      } else {
        asrc = A + (size_t)(m0 + row) * K + k0 + col;
      }
      gload16(asrc, &As[(i * 256 + tid) * 8]);
    }
#pragma unroll
    for (int i = 0; i < 4; i++) {
      int row = i * 32 + srow;
      int col = ((scb ^ (row & 7)) << 3);
      gload16(B + (size_t)(n0 + row) * K + k0 + col, &Bs[(i * 256 + tid) * 8]);
    }
  };

  for (int k0 = 0; k0 < K; k0 += 64) {
    __syncthreads();
    stage(k0);
    __syncthreads();
#pragma unroll
    for (int kk = 0; kk < 4; kk++) {
      u32x4 af[MI], bfr[2];
#pragma unroll
      for (int mi = 0; mi < MI; mi++) {
        int row = wr + mi * 32 + r31;
        int cb = (kk * 2 + hi) ^ (row & 7);
        af[mi] = *(const u32x4*)&As[row * 64 + cb * 8];
      }
#pragma unroll
      for (int ni = 0; ni < 2; ni++) {
        int row = wc + ni * 32 + r31;
        int cb = (kk * 2 + hi) ^ (row & 7);
        bfr[ni] = *(const u32x4*)&Bs[row * 64 + cb * 8];
      }
#pragma unroll
      for (int mi = 0; mi < MI; mi++)
#pragma unroll
        for (int ni = 0; ni < 2; ni++)
          acc[mi][ni] = mfma32(af[mi], bfr[ni], acc[mi][ni]);
    }
  }

  if constexpr (EPI == 0) {
#pragma unroll
    for (int mi = 0; mi < MI; mi++) {
#pragma unroll
      for (int ni = 0; ni < 2; ni++) {
        int n = n0 + wc + ni * 32 + r31;
        int which = n >> 9, h = (n >> 6) & 7, dh = n & 63;
        const float* bp = (which == 0) ? b0 : (which == 1) ? b1 : b2;
        float bias = bp[n & 511];
#pragma unroll
        for (int grp = 0; grp < 4; grp++) {
          int mbase = m0 + wr + mi * 32 + grp * 8 + hi * 4;
          int bb = mbase >> 10, aa = mbase & 1023;
          int bh = bb * 8 + h;
          u16x4 pk;
#pragma unroll
          for (int j = 0; j < 4; j++) pk[j] = f2bf(acc[mi][ni][grp * 4 + j] + bias);
          if (which < 2) {
            u16* dstr = ((which == 0) ? o0 : o1) + ((size_t)bh * 1024 + aa) * 64 + dh;
#pragma unroll
            for (int j = 0; j < 4; j++) dstr[(size_t)j * 64] = pk[j];
            u16* dstt = ((which == 0) ? qt : kt) + ((size_t)bh * 64 + dh) * 1024 + aa;
            *(u16x4*)dstt = pk;
          } else {
            *(u16x4*)(o2 + ((size_t)bh * 64 + dh) * 1024 + aa) = pk;
          }
        }
      }
    }
  } else if constexpr (EPI == 1) {
#pragma unroll
    for (int mi = 0; mi < MI; mi++) {
#pragma unroll
      for (int ni = 0; ni < 2; ni++) {
        int n = n0 + wc + ni * 32 + r31;
        float bias = b0[n];
#pragma unroll
        for (int i = 0; i < 16; i++) {
          int m = m0 + wr + mi * 32 + (i & 3) + 8 * (i >> 2) + 4 * hi;
          float v = acc[mi][ni][i] + bias;
          v = 0.5f * v * (1.0f + erff(v * 0.70710678118654752f));
          o0[(size_t)m * 1024 + n] = f2bf(v);
        }
      }
    }
  } else {
#pragma unroll
    for (int mi = 0; mi < MI; mi++) {
#pragma unroll
      for (int ni = 0; ni < 2; ni++) {
        int n = n0 + wc + ni * 32 + r31;
        float bias = b0[n];
#pragma unroll
        for (int i = 0; i < 16; i++) {
          int m = m0 + wr + mi * 32 + (i & 3) + 8 * (i >> 2) + 4 * hi;
          float v = acc[mi][ni][i] + bias + bf2f(resid[(size_t)m * 512 + n]);
          outf[(size_t)m * 512 + n] = v;
        }
      }
    }
  }
}

// ---------------- fused MFMA gram (unchanged) ----------------
__global__ __launch_bounds__(256) void k_gram2(const u16* __restrict__ qt,
                                               const u16* __restrict__ kt,
                                               float* __restrict__ stats) {
  __shared__ __align__(16) u16 Xq[2][64 * 64];
  __shared__ __align__(16) u16 Xk[2][64 * 64];
  __shared__ float red[8];
  int tid = threadIdx.x, wid = tid >> 6, lane = tid & 63;
  int g = lane >> 4, c = lane & 15;
  int bh = blockIdx.x;
  const int srow = tid >> 3, scb = tid & 7;
  const u32x4 ones = {0x3F803F80u, 0x3F803F80u, 0x3F803F80u, 0x3F803F80u};
  const f32x4 zero = {0.f, 0.f, 0.f, 0.f};
  const u16* qsrc = qt + ((size_t)bh << 16);
  const u16* ksrc = kt + ((size_t)bh << 16);

  f32x4 gq[4], gk[4], csq = zero, csk = zero;
#pragma unroll
  for (int j = 0; j < 4; j++) {
    gq[j] = zero;
    gk[j] = zero;
  }

  auto stage = [&](int buf, int k0) {
#pragma unroll
    for (int i = 0; i < 2; i++) {
      int row = i * 32 + srow;
      int col = ((scb ^ (row & 7)) << 3);
      gload16(qsrc + (size_t)row * 1024 + k0 + col, &Xq[buf][(i * 256 + tid) * 8]);
      gload16(ksrc + (size_t)row * 1024 + k0 + col, &Xk[buf][(i * 256 + tid) * 8]);
    }
  };

  stage(0, 0);
  int cur = 0;
  for (int k0 = 0; k0 < 1024; k0 += 64) {
    __syncthreads();
    if (k0 + 64 < 1024) stage(cur ^ 1, k0 + 64);
#pragma unroll
    for (int kk = 0; kk < 2; kk++) {
      int arow = wid * 16 + c;
      int cba = (kk * 4 + g) ^ (arow & 7);
      u32x4 aq = *(const u32x4*)&Xq[cur][arow * 64 + cba * 8];
      u32x4 ak = *(const u32x4*)&Xk[cur][arow * 64 + cba * 8];
      csq = mfma16(aq, ones, csq);
      csk = mfma16(ak, ones, csk);
#pragma unroll
      for (int ni = 0; ni < 4; ni++) {
        int brow = ni * 16 + c;
        int cbb = (kk * 4 + g) ^ (brow & 7);
        u32x4 bq = *(const u32x4*)&Xq[cur][brow * 64 + cbb * 8];
        u32x4 bk = *(const u32x4*)&Xk[cur][brow * 64 + cbb * 8];
        gq[ni] = mfma16(aq, bq, gq[ni]);
        gk[ni] = mfma16(ak, bk, gk[ni]);
      }
    }
    cur ^= 1;
  }
  float part = 0.f;
#pragma unroll
  for (int ni = 0; ni < 4; ni++)
#pragma unroll
    for (int r = 0; r < 4; r++) part += gq[ni][r] * gk[ni][r];
  part = wred(part);
  float cpart = 0.f;
  if (c == 0) {
#pragma unroll
    for (int r = 0; r < 4; r++) cpart += csq[r] * csk[r];
  }
  cpart = wred(cpart);
  if (lane == 0) {
    red[wid] = part;
    red[4 + wid] = cpart;
  }
  __syncthreads();
  if (tid == 0) {
    stats[bh * 2] = red[0] + red[1] + red[2] + red[3];
    stats[bh * 2 + 1] = red[4] + red[5] + red[6] + red[7];
  }
}

// ---------------- flash attention (unchanged from R14) ----------------
DEVI float tilemax(const f32x16& st) {
  float m1 = fmaxf(fmaxf(st[0], st[1]), st[2]);
  float m2 = fmaxf(fmaxf(st[3], st[4]), st[5]);
  float m3 = fmaxf(fmaxf(st[6], st[7]), st[8]);
  float m4 = fmaxf(fmaxf(st[9], st[10]), st[11]);
  float m5 = fmaxf(fmaxf(st[12], st[13]), st[14]);
  float ta = fmaxf(fmaxf(m1, m2), m3);
  float tb = fmaxf(fmaxf(m4, m5), st[15]);
  return fmaxf(ta, tb);
}

DEVI void check_rescale(const f32x16& st, float& m_run, f32x16& oa, f32x16& ob,
                        f32x16& lacc) {
  float pm = xmax2(tilemax(st));
  if (__any(pm > m_run + 8.0f)) {
    float mnew = fmaxf(m_run, pm);
    float al = ex2(m_run - mnew);
    lacc[0] *= al;
#pragma unroll
    for (int i = 0; i < 16; i++) {
      oa[i] *= al;
      ob[i] *= al;
    }
    m_run = mnew;
  }
}

DEVI u32x4 packp(const float* p, int ks) {
  uint32_t A0 = cvtpk(p[ks * 8 + 0], p[ks * 8 + 1]);
  uint32_t A1 = cvtpk(p[ks * 8 + 4], p[ks * 8 + 5]);
  plswap(A0, A1);
  uint32_t B0 = cvtpk(p[ks * 8 + 2], p[ks * 8 + 3]);
  uint32_t B1 = cvtpk(p[ks * 8 + 6], p[ks * 8 + 7]);
  plswap(B0, B1);
  u32x4 pa = {A0, B0, A1, B1};
  return pa;
}

__global__ __launch_bounds__(256, 2) void k_attn(const u16* __restrict__ q,
                                                 const u16* __restrict__ k,
                                                 const u16* __restrict__ vt,
                                                 const float* __restrict__ stats,
                                                 u16* __restrict__ ao) {
  __shared__ __align__(16) u16 Ks[2][64 * 64];
  __shared__ __align__(16) u16 Vs[2][64 * 64];
  int tid = threadIdx.x, wid = tid >> 6, lane = tid & 63;
  int r = lane & 31, hi = lane >> 5, h8 = hi * 8;
  int bh = blockIdx.x, qt = blockIdx.y;
  int b = bh >> 3, h = bh & 7;
  float ssq = 0.f, sm = 0.f;
#pragma unroll
  for (int bb2 = 0; bb2 < 16; bb2++) {
    ssq += stats[(bb2 * 8 + h) * 2];
    sm += stats[(bb2 * 8 + h) * 2 + 1];
  }
  const float NN = 16777216.0f;
  float var = (ssq - sm * sm / NN) / (NN - 1.0f);
  float sd = sqrtf(fmaxf(var, 0.0f));
  float sc = 1.4426950408889634f / (8.0f * sqrtf(1.0f + sd));
  int q0 = qt * 256 + wid * 32;  // tile1 rows; tile2 = q0 + 128
  const u16* qb = q + ((size_t)bh << 16);
  const u16* kb = k + ((size_t)bh << 16);
  const u16* vb = vt + ((size_t)bh << 16);
  const int srow = tid >> 3, scb = tid & 7;
  const u32x4 ones = {0x3F803F80u, 0x3F803F80u, 0x3F803F80u, 0x3F803F80u};

  u32x4 qf1[4], qf2[4];
#pragma unroll
  for (int tt = 0; tt < 2; tt++) {
    const u16* qrow = qb + (size_t)(q0 + tt * 128 + r) * 64 + h8;
#pragma unroll
    for (int ks = 0; ks < 4; ks++) {
      u32x4 raw = *(const u32x4*)(qrow + ks * 16);
      u32x4 w;
#pragma unroll
      for (int t = 0; t < 4; t++) {
        float lo = bf2f((u16)(raw[t] & 0xffffu)) * sc;
        float hi_ = bf2f((u16)(raw[t] >> 16)) * sc;
        w[t] = cvtpk(lo, hi_);
      }
      if (tt == 0)
        qf1[ks] = w;
      else
        qf2[ks] = w;
    }
  }

  const f32x16 zero16 = {0.f, 0.f, 0.f, 0.f, 0.f, 0.f, 0.f, 0.f,
                         0.f, 0.f, 0.f, 0.f, 0.f, 0.f, 0.f, 0.f};
  f32x16 o0 = zero16, o1 = zero16, o2 = zero16, o3 = zero16;
  f32x16 lacc1 = zero16, lacc2 = zero16;
  float m1 = -1e30f, m2 = -1e30f;

  auto stage = [&](int buf, int t0) {
#pragma unroll
    for (int i = 0; i < 2; i++) {
      int row = i * 32 + srow;
      int col = ((scb ^ (row & 7)) << 3);
      gload16(kb + (size_t)(t0 + row) * 64 + col, &Ks[buf][(i * 256 + tid) * 8]);
      gload16(vb + (size_t)row * 1024 + t0 + col, &Vs[buf][(i * 256 + tid) * 8]);
    }
  };

  stage(0, 0);
  int cur = 0;
  for (int t0 = 0; t0 < 1024; t0 += 64) {
    __syncthreads();
    if (t0 + 64 < 1024) stage(cur ^ 1, t0 + 64);
    const u16* Kc = Ks[cur];
    const u16* Vc = Vs[cur];
#pragma unroll
    for (int ss = 0; ss < 2; ss++) {
      int rk = ss * 32 + r;
      u32x4 kf[4];
#pragma unroll
      for (int ks = 0; ks < 4; ks++) {
        int cb = (ks * 2 + hi) ^ (rk & 7);
        kf[ks] = *(const u32x4*)&Kc[rk * 64 + cb * 8];
      }
      f32x16 st1 = zero16, st2 = zero16;
      __builtin_amdgcn_s_setprio(1);
#pragma unroll
      for (int ks = 0; ks < 4; ks++) st1 = mfma32(kf[ks], qf1[ks], st1);
#pragma unroll
      for (int ks = 0; ks < 4; ks++) st2 = mfma32(kf[ks], qf2[ks], st2);
      __builtin_amdgcn_s_setprio(0);
      if (ss == 1 || t0 == 0) {
        check_rescale(st1, m1, o0, o1, lacc1);
        check_rescale(st2, m2, o2, o3, lacc2);
      }
      float p1[16], p2[16];
#pragma unroll
      for (int i = 0; i < 16; i++) p1[i] = ex2(st1[i] - m1);
#pragma unroll
      for (int i = 0; i < 16; i++) p2[i] = ex2(st2[i] - m2);
      __builtin_amdgcn_s_setprio(1);
#pragma unroll
      for (int ks = 0; ks < 2; ks++) {
        u32x4 pa1 = packp(p1, ks);
        u32x4 pa2 = packp(p2, ks);
        lacc1 = mfma32(ones, pa1, lacc1);
        lacc2 = mfma32(ones, pa2, lacc2);
#pragma unroll
        for (int mt = 0; mt < 2; mt++) {
          int rv = mt * 32 + r;
          int cb = (ss * 4 + ks * 2 + hi) ^ (rv & 7);
          u32x4 vf = *(const u32x4*)&Vc[rv * 64 + cb * 8];
          if (mt == 0) {
            o0 = mfma32(vf, pa1, o0);
            o2 = mfma32(vf, pa2, o2);
          } else {
            o1 = mfma32(vf, pa1, o1);
            o3 = mfma32(vf, pa2, o3);
          }
        }
      }
      __builtin_amdgcn_s_setprio(0);
    }
    cur ^= 1;
  }

  float inv1 = 1.0f / lacc1[0];
  float inv2 = 1.0f / lacc2[0];
#pragma unroll
  for (int tt = 0; tt < 2; tt++) {
    int a_idx = q0 + tt * 128 + r;
    u16* aop = ao + ((size_t)(a_idx * 16 + b)) * 512 + h * 64;
    float inv = tt == 0 ? inv1 : inv2;
#pragma unroll
    for (int i = 0; i < 16; i++) {
      int dh0 = (i & 3) + 8 * (i >> 2) + 4 * hi;
      if (tt == 0) {
        aop[dh0] = f2bf(o0[i] * inv);
        aop[32 + dh0] = f2bf(o1[i] * inv);
      } else {
        aop[dh0] = f2bf(o2[i] * inv);
        aop[32 + dh0] = f2bf(o3[i] * inv);
      }
    }
  }
}

extern "C" void kernel_launch(void* const* d_in, const int* in_sizes, int n_in,
                              void* d_out, int out_size, void* d_ws, size_t ws_size,
                              hipStream_t stream) {
  const float* x = (const float*)d_in[0];
  const float* Wq = (const float*)d_in[1];
  const float* bq = (const float*)d_in[2];
  const float* Wk = (const float*)d_in[3];
  const float* bk = (const float*)d_in[4];
  const float* Wv = (const float*)d_in[5];
  const float* bv = (const float*)d_in[6];
  const float* g1 = (const float*)d_in[7];
  const float* be1 = (const float*)d_in[8];
  const float* g2 = (const float*)d_in[9];
  const float* be2 = (const float*)d_in[10];
  const float* W1 = (const float*)d_in[11];
  const float* bf1 = (const float*)d_in[12];
  const float* W2 = (const float*)d_in[13];
  const float* bf2v = (const float*)d_in[14];
  float* out = (float*)d_out;

  char* w = (char*)d_ws;
  size_t off = 0;
  auto alloc = [&](size_t bytes) -> void* {
    void* p = w + off;
    off += (bytes + 255) & ~(size_t)255;
    return p;
  };
  u16* xn_res = (u16*)alloc(16384ull * 512 * 2);
  u16* qbuf = (u16*)alloc(128ull * 1024 * 64 * 2);
  u16* kbuf = (u16*)alloc(128ull * 1024 * 64 * 2);
  u16* vtb = (u16*)alloc(128ull * 64 * 1024 * 2);
  u16* qtb = (u16*)alloc(128ull * 64 * 1024 * 2);
  u16* ktb = (u16*)alloc(128ull * 64 * 1024 * 2);
  u16* wqkv_t = (u16*)alloc(1536ull * 512 * 2);
  u16* w1t = (u16*)alloc(1024ull * 512 * 2);
  u16* w2t = (u16*)alloc(512ull * 1024 * 2);
  u16* h_bf = (u16*)alloc(16384ull * 1024 * 2);
  float* stats = (float*)alloc(128ull * 2 * 4);
  u16* ao_bf = (u16*)alloc(16384ull * 512 * 2);
  u16* xt_bf = (u16*)alloc(16384ull * 512 * 2);

  k_prep_ln1<<<448 + 4096, 256, 0, stream>>>(Wq, Wk, Wv, W1, W2, x, g1, be1,
                                             wqkv_t, w1t, w2t, xn_res);

  k_gemm<0, 128, 12><<<1536, 256, 0, stream>>>(
      xn_res, wqkv_t, 512, 192, bq, bk, bv, qbuf, kbuf, vtb, qtb, ktb, nullptr,
      nullptr);

  k_gram2<<<128, 256, 0, stream>>>(qtb, ktb, stats);

  k_attn<<<dim3(128, 4), 256, 0, stream>>>(qbuf, kbuf, vtb, stats, ao_bf);

  k_ln2<<<4096, 256, 0, stream>>>(xn_res, ao_bf, g2, be2, xt_bf);

  k_gemm<1, 128, 8><<<1024, 256, 0, stream>>>(
      xt_bf, w1t, 512, 128, bf1, nullptr, nullptr, h_bf, nullptr, nullptr,
      nullptr, nullptr, nullptr, nullptr);
  k_gemm<2, 64, 4><<<1024, 256, 0, stream>>>(
      h_bf, w2t, 1024, 128, bf2v, nullptr, nullptr, nullptr, nullptr, nullptr,
      nullptr, nullptr, xt_bf, out);
  (void)in_sizes; (void)n_in; (void)out_size; (void)ws_size;
}

// Round 17
// 197.326 us; speedup vs baseline: 1.1312x; 1.1312x over previous
//
#include <hip/hip_runtime.h>
#include <stdint.h>

typedef unsigned short u16;
typedef u16 u16x4 __attribute__((ext_vector_type(4)));
typedef unsigned int u32x4 __attribute__((ext_vector_type(4)));
typedef float f32x4 __attribute__((ext_vector_type(4)));
typedef float f32x16 __attribute__((ext_vector_type(16)));
typedef __bf16 bf16x8 __attribute__((ext_vector_type(8)));

#define DEVI __device__ __forceinline__

DEVI u16 f2bf(float f) {
  uint32_t u = __builtin_bit_cast(uint32_t, f);
  u = (u + 0x7FFFu + ((u >> 16) & 1u)) >> 16;
  return (u16)u;
}
DEVI float bf2f(u16 h) {
  uint32_t u = ((uint32_t)h) << 16;
  return __builtin_bit_cast(float, u);
}
DEVI f32x4 mfma16(u32x4 a, u32x4 b, f32x4 c) {
  return __builtin_amdgcn_mfma_f32_16x16x32_bf16(
      __builtin_bit_cast(bf16x8, a), __builtin_bit_cast(bf16x8, b), c, 0, 0, 0);
}
DEVI f32x16 mfma32(u32x4 a, u32x4 b, f32x16 c) {
  return __builtin_amdgcn_mfma_f32_32x32x16_bf16(
      __builtin_bit_cast(bf16x8, a), __builtin_bit_cast(bf16x8, b), c, 0, 0, 0);
}
DEVI uint32_t cvtpk(float lo, float hi) {
  uint32_t w;
  asm("v_cvt_pk_bf16_f32 %0, %1, %2" : "=v"(w) : "v"(lo), "v"(hi));
  return w;
}
DEVI void plswap(uint32_t& a, uint32_t& b) {
  asm("v_permlane32_swap_b32 %0, %1" : "+v"(a), "+v"(b));
}
DEVI float xmax2(float v) {
  uint32_t a = __builtin_bit_cast(uint32_t, v), b = a;
  plswap(a, b);
  return fmaxf(__builtin_bit_cast(float, a), __builtin_bit_cast(float, b));
}
DEVI float ex2(float x) { return __builtin_amdgcn_exp2f(x); }

#define AS1 __attribute__((address_space(1)))
#define AS3 __attribute__((address_space(3)))
DEVI void gload16(const void* g, void* l) {
  __builtin_amdgcn_global_load_lds((AS1 void*)(uintptr_t)g,
                                   (AS3 void*)(uint32_t)(uintptr_t)l, 16, 0, 0);
}

DEVI float wred(float v) {
#pragma unroll
  for (int m = 1; m < 64; m <<= 1) v += __shfl_xor(v, m);
  return v;
}

// ---------------- merged prep (5 weight transposes) + LN1 in ONE launch -------------
__global__ __launch_bounds__(256) void k_prep_ln1(
    const float* __restrict__ Wq, const float* __restrict__ Wk,
    const float* __restrict__ Wv, const float* __restrict__ W1,
    const float* __restrict__ W2, const float* __restrict__ x,
    const float* __restrict__ gam, const float* __restrict__ bet,
    u16* __restrict__ wqkv_t, u16* __restrict__ w1t, u16* __restrict__ w2t,
    u16* __restrict__ xn_res) {
  __shared__ float tile[64][65];
  int bid = blockIdx.x, tid = threadIdx.x;
  if (bid < 448) {
    const float* W;
    u16* Wt;
    int Kr, Nc, n0, k0;
    if (bid < 192) {
      int w = bid / 64, t = bid & 63;
      W = (w == 0) ? Wq : (w == 1) ? Wk : Wv;
      Wt = wqkv_t + (size_t)w * 512 * 512;
      Kr = 512; Nc = 512; n0 = (t & 7) * 64; k0 = (t >> 3) * 64;
    } else if (bid < 320) {
      int t = bid - 192;
      W = W1; Wt = w1t;
      Kr = 512; Nc = 1024; n0 = (t & 15) * 64; k0 = (t >> 4) * 64;
    } else {
      int t = bid - 320;
      W = W2; Wt = w2t;
      Kr = 1024; Nc = 512; n0 = (t & 7) * 64; k0 = (t >> 3) * 64;
    }
#pragma unroll
    for (int i = 0; i < 16; i++) {
      int idx = i * 256 + tid;
      int r = idx >> 6, cc = idx & 63;
      tile[r][cc] = W[(size_t)(k0 + r) * Nc + n0 + cc];
    }
    __syncthreads();
#pragma unroll
    for (int i = 0; i < 16; i++) {
      int idx = i * 256 + tid;
      int r = idx >> 6, cc = idx & 63;
      Wt[(size_t)(n0 + r) * Kr + k0 + cc] = f2bf(tile[cc][r]);
    }
  } else {
    int wid = tid >> 6, lane = tid & 63;
    int row = (bid - 448) * 4 + wid;
    const float* xr = x + (size_t)row * 512 + lane * 8;
    f32x4 v0 = *(const f32x4*)xr;
    f32x4 v1 = *(const f32x4*)(xr + 4);
    float s = 0.f, ss = 0.f;
#pragma unroll
    for (int j = 0; j < 4; j++) {
      s += v0[j] + v1[j];
      ss += v0[j] * v0[j] + v1[j] * v1[j];
    }
    s = wred(s);
    ss = wred(ss);
    float mean = s * (1.0f / 512.0f);
    float var = ss * (1.0f / 512.0f) - mean * mean;
    float rstd = rsqrtf(var + 1e-5f);
    const float* gp = gam + lane * 8;
    const float* bp = bet + lane * 8;
    f32x4 ga = *(const f32x4*)gp, gb = *(const f32x4*)(gp + 4);
    f32x4 ba = *(const f32x4*)bp, bb = *(const f32x4*)(bp + 4);
    u16x4 o0, o1;
#pragma unroll
    for (int j = 0; j < 4; j++) {
      o0[j] = f2bf((v0[j] - mean) * rstd * ga[j] + ba[j]);
      o1[j] = f2bf((v1[j] - mean) * rstd * gb[j] + bb[j]);
    }
    u16* pr = xn_res + (size_t)row * 512 + lane * 8;
    *(u16x4*)pr = o0;
    *(u16x4*)(pr + 4) = o1;
  }
}

// ---------------- LN2 ----------------
__global__ __launch_bounds__(256) void k_ln2(const u16* __restrict__ xn,
                                             const u16* __restrict__ ao,
                                             const float* __restrict__ gam,
                                             const float* __restrict__ bet,
                                             u16* __restrict__ xt) {
  int tid = threadIdx.x, wid = tid >> 6, lane = tid & 63;
  int row = blockIdx.x * 4 + wid;
  size_t base = (size_t)row * 512 + lane * 8;
  u16x4 a0 = *(const u16x4*)&xn[base], a1 = *(const u16x4*)&xn[base + 4];
  u16x4 c0 = *(const u16x4*)&ao[base], c1 = *(const u16x4*)&ao[base + 4];
  float v[8];
#pragma unroll
  for (int j = 0; j < 4; j++) {
    v[j] = bf2f(a0[j]) + bf2f(c0[j]);
    v[4 + j] = bf2f(a1[j]) + bf2f(c1[j]);
  }
  float s = 0.f, ss = 0.f;
#pragma unroll
  for (int j = 0; j < 8; j++) {
    s += v[j];
    ss += v[j] * v[j];
  }
  s = wred(s);
  ss = wred(ss);
  float mean = s * (1.0f / 512.0f);
  float var = ss * (1.0f / 512.0f) - mean * mean;
  float rstd = rsqrtf(var + 1e-5f);
  const float* gp = gam + lane * 8;
  const float* bp = bet + lane * 8;
  u16x4 o0, o1;
#pragma unroll
  for (int j = 0; j < 4; j++) {
    o0[j] = f2bf((v[j] - mean) * rstd * gp[j] + bp[j]);
    o1[j] = f2bf((v[4 + j] - mean) * rstd * gp[4 + j] + bp[4 + j]);
  }
  u16* pr = xt + base;
  *(u16x4*)pr = o0;
  *(u16x4*)(pr + 4) = o1;
}

// ---------------- GEMM C = A * B^T, BM x 128 tile, BK=64, 32x32 MFMA ----------------
// R14-validated launch shape: bounds (256, BM==64?4:3), 1D grid + XCD swizzle.
template <int EPI, int BM, int NB>
__global__ __launch_bounds__(256, BM == 64 ? 4 : 3) void k_gemm(
    const u16* __restrict__ A, const u16* __restrict__ B, int K, int nwg8,
    const float* __restrict__ b0, const float* __restrict__ b1,
    const float* __restrict__ b2, u16* __restrict__ o0, u16* __restrict__ o1,
    u16* __restrict__ o2, u16* __restrict__ qt, u16* __restrict__ kt,
    const u16* __restrict__ resid, float* __restrict__ outf) {
  constexpr int MI = BM / 64;
  __shared__ __align__(16) u16 As[BM * 64];
  __shared__ __align__(16) u16 Bs[128 * 64];
  const int tid = threadIdx.x;
  const int wid = tid >> 6, lane = tid & 63;
  const int r31 = lane & 31, hi = lane >> 5;
  const int bid = blockIdx.x;
  const int oid = (bid & 7) * nwg8 + (bid >> 3);
  const int m0 = (oid / NB) * BM, n0 = (oid % NB) * 128;
  const int wr = (wid >> 1) * (BM / 2), wc = (wid & 1) * 64;
  const int srow = tid >> 3, scb = tid & 7;

  f32x16 acc[MI][2];
#pragma unroll
  for (int i = 0; i < MI; i++)
#pragma unroll
    for (int j = 0; j < 2; j++)
#pragma unroll
      for (int e = 0; e < 16; e++) acc[i][j][e] = 0.f;

  auto stage = [&](int k0) {
#pragma unroll
    for (int i = 0; i < BM / 32; i++) {
      int row = i * 32 + srow;
      int col = ((scb ^ (row & 7)) << 3);
      const u16* asrc;
      if constexpr (EPI == 0) {
        int m = m0 + row;  // m = b*1024+a; source row = token a*16+b
        asrc = A + ((size_t)(((m & 1023) << 4) | (m >> 10))) * K + k0 + col;
      } else {
        asrc = A + (size_t)(m0 + row) * K + k0 + col;
      }
      gload16(asrc, &As[(i * 256 + tid) * 8]);
    }
#pragma unroll
    for (int i = 0; i < 4; i++) {
      int row = i * 32 + srow;
      int col = ((scb ^ (row & 7)) << 3);
      gload16(B + (size_t)(n0 + row) * K + k0 + col, &Bs[(i * 256 + tid) * 8]);
    }
  };

  for (int k0 = 0; k0 < K; k0 += 64) {
    __syncthreads();
    stage(k0);
    __syncthreads();
#pragma unroll
    for (int kk = 0; kk < 4; kk++) {
      u32x4 af[MI], bfr[2];
#pragma unroll
      for (int mi = 0; mi < MI; mi++) {
        int row = wr + mi * 32 + r31;
        int cb = (kk * 2 + hi) ^ (row & 7);
        af[mi] = *(const u32x4*)&As[row * 64 + cb * 8];
      }
#pragma unroll
      for (int ni = 0; ni < 2; ni++) {
        int row = wc + ni * 32 + r31;
        int cb = (kk * 2 + hi) ^ (row & 7);
        bfr[ni] = *(const u32x4*)&Bs[row * 64 + cb * 8];
      }
#pragma unroll
      for (int mi = 0; mi < MI; mi++)
#pragma unroll
        for (int ni = 0; ni < 2; ni++)
          acc[mi][ni] = mfma32(af[mi], bfr[ni], acc[mi][ni]);
    }
  }

  if constexpr (EPI == 0) {
#pragma unroll
    for (int mi = 0; mi < MI; mi++) {
#pragma unroll
      for (int ni = 0; ni < 2; ni++) {
        int n = n0 + wc + ni * 32 + r31;
        int which = n >> 9, h = (n >> 6) & 7, dh = n & 63;
        const float* bp = (which == 0) ? b0 : (which == 1) ? b1 : b2;
        float bias = bp[n & 511];
#pragma unroll
        for (int grp = 0; grp < 4; grp++) {
          int mbase = m0 + wr + mi * 32 + grp * 8 + hi * 4;
          int bb = mbase >> 10, aa = mbase & 1023;
          int bh = bb * 8 + h;
          u16x4 pk;
#pragma unroll
          for (int j = 0; j < 4; j++) pk[j] = f2bf(acc[mi][ni][grp * 4 + j] + bias);
          if (which < 2) {
            u16* dstr = ((which == 0) ? o0 : o1) + ((size_t)bh * 1024 + aa) * 64 + dh;
#pragma unroll
            for (int j = 0; j < 4; j++) dstr[(size_t)j * 64] = pk[j];
            u16* dstt = ((which == 0) ? qt : kt) + ((size_t)bh * 64 + dh) * 1024 + aa;
            *(u16x4*)dstt = pk;
          } else {
            *(u16x4*)(o2 + ((size_t)bh * 64 + dh) * 1024 + aa) = pk;
          }
        }
      }
    }
  } else if constexpr (EPI == 1) {
#pragma unroll
    for (int mi = 0; mi < MI; mi++) {
#pragma unroll
      for (int ni = 0; ni < 2; ni++) {
        int n = n0 + wc + ni * 32 + r31;
        float bias = b0[n];
#pragma unroll
        for (int i = 0; i < 16; i++) {
          int m = m0 + wr + mi * 32 + (i & 3) + 8 * (i >> 2) + 4 * hi;
          float v = acc[mi][ni][i] + bias;
          v = 0.5f * v * (1.0f + erff(v * 0.70710678118654752f));
          o0[(size_t)m * 1024 + n] = f2bf(v);
        }
      }
    }
  } else {
#pragma unroll
    for (int mi = 0; mi < MI; mi++) {
#pragma unroll
      for (int ni = 0; ni < 2; ni++) {
        int n = n0 + wc + ni * 32 + r31;
        float bias = b0[n];
#pragma unroll
        for (int i = 0; i < 16; i++) {
          int m = m0 + wr + mi * 32 + (i & 3) + 8 * (i >> 2) + 4 * hi;
          float v = acc[mi][ni][i] + bias + bf2f(resid[(size_t)m * 512 + n]);
          outf[(size_t)m * 512 + n] = v;
        }
      }
    }
  }
}

// ---------------- fused MFMA gram (unchanged) ----------------
__global__ __launch_bounds__(256) void k_gram2(const u16* __restrict__ qt,
                                               const u16* __restrict__ kt,
                                               float* __restrict__ stats) {
  __shared__ __align__(16) u16 Xq[2][64 * 64];
  __shared__ __align__(16) u16 Xk[2][64 * 64];
  __shared__ float red[8];
  int tid = threadIdx.x, wid = tid >> 6, lane = tid & 63;
  int g = lane >> 4, c = lane & 15;
  int bh = blockIdx.x;
  const int srow = tid >> 3, scb = tid & 7;
  const u32x4 ones = {0x3F803F80u, 0x3F803F80u, 0x3F803F80u, 0x3F803F80u};
  const f32x4 zero = {0.f, 0.f, 0.f, 0.f};
  const u16* qsrc = qt + ((size_t)bh << 16);
  const u16* ksrc = kt + ((size_t)bh << 16);

  f32x4 gq[4], gk[4], csq = zero, csk = zero;
#pragma unroll
  for (int j = 0; j < 4; j++) {
    gq[j] = zero;
    gk[j] = zero;
  }

  auto stage = [&](int buf, int k0) {
#pragma unroll
    for (int i = 0; i < 2; i++) {
      int row = i * 32 + srow;
      int col = ((scb ^ (row & 7)) << 3);
      gload16(qsrc + (size_t)row * 1024 + k0 + col, &Xq[buf][(i * 256 + tid) * 8]);
      gload16(ksrc + (size_t)row * 1024 + k0 + col, &Xk[buf][(i * 256 + tid) * 8]);
    }
  };

  stage(0, 0);
  int cur = 0;
  for (int k0 = 0; k0 < 1024; k0 += 64) {
    __syncthreads();
    if (k0 + 64 < 1024) stage(cur ^ 1, k0 + 64);
#pragma unroll
    for (int kk = 0; kk < 2; kk++) {
      int arow = wid * 16 + c;
      int cba = (kk * 4 + g) ^ (arow & 7);
      u32x4 aq = *(const u32x4*)&Xq[cur][arow * 64 + cba * 8];
      u32x4 ak = *(const u32x4*)&Xk[cur][arow * 64 + cba * 8];
      csq = mfma16(aq, ones, csq);
      csk = mfma16(ak, ones, csk);
#pragma unroll
      for (int ni = 0; ni < 4; ni++) {
        int brow = ni * 16 + c;
        int cbb = (kk * 4 + g) ^ (brow & 7);
        u32x4 bq = *(const u32x4*)&Xq[cur][brow * 64 + cbb * 8];
        u32x4 bk = *(const u32x4*)&Xk[cur][brow * 64 + cbb * 8];
        gq[ni] = mfma16(aq, bq, gq[ni]);
        gk[ni] = mfma16(ak, bk, gk[ni]);
      }
    }
    cur ^= 1;
  }
  float part = 0.f;
#pragma unroll
  for (int ni = 0; ni < 4; ni++)
#pragma unroll
    for (int r = 0; r < 4; r++) part += gq[ni][r] * gk[ni][r];
  part = wred(part);
  float cpart = 0.f;
  if (c == 0) {
#pragma unroll
    for (int r = 0; r < 4; r++) cpart += csq[r] * csk[r];
  }
  cpart = wred(cpart);
  if (lane == 0) {
    red[wid] = part;
    red[4 + wid] = cpart;
  }
  __syncthreads();
  if (tid == 0) {
    stats[bh * 2] = red[0] + red[1] + red[2] + red[3];
    stats[bh * 2 + 1] = red[4] + red[5] + red[6] + red[7];
  }
}

// ---------------- flash attention (R14-validated) ----------------
DEVI float tilemax(const f32x16& st) {
  float m1 = fmaxf(fmaxf(st[0], st[1]), st[2]);
  float m2 = fmaxf(fmaxf(st[3], st[4]), st[5]);
  float m3 = fmaxf(fmaxf(st[6], st[7]), st[8]);
  float m4 = fmaxf(fmaxf(st[9], st[10]), st[11]);
  float m5 = fmaxf(fmaxf(st[12], st[13]), st[14]);
  float ta = fmaxf(fmaxf(m1, m2), m3);
  float tb = fmaxf(fmaxf(m4, m5), st[15]);
  return fmaxf(ta, tb);
}

DEVI void check_rescale(const f32x16& st, float& m_run, f32x16& oa, f32x16& ob,
                        f32x16& lacc) {
  float pm = xmax2(tilemax(st));
  if (__any(pm > m_run + 8.0f)) {
    float mnew = fmaxf(m_run, pm);
    float al = ex2(m_run - mnew);
    lacc[0] *= al;
#pragma unroll
    for (int i = 0; i < 16; i++) {
      oa[i] *= al;
      ob[i] *= al;
    }
    m_run = mnew;
  }
}

DEVI u32x4 packp(const float* p, int ks) {
  uint32_t A0 = cvtpk(p[ks * 8 + 0], p[ks * 8 + 1]);
  uint32_t A1 = cvtpk(p[ks * 8 + 4], p[ks * 8 + 5]);
  plswap(A0, A1);
  uint32_t B0 = cvtpk(p[ks * 8 + 2], p[ks * 8 + 3]);
  uint32_t B1 = cvtpk(p[ks * 8 + 6], p[ks * 8 + 7]);
  plswap(B0, B1);
  u32x4 pa = {A0, B0, A1, B1};
  return pa;
}

__global__ __launch_bounds__(256, 2) void k_attn(const u16* __restrict__ q,
                                                 const u16* __restrict__ k,
                                                 const u16* __restrict__ vt,
                                                 const float* __restrict__ stats,
                                                 u16* __restrict__ ao) {
  __shared__ __align__(16) u16 Ks[2][64 * 64];
  __shared__ __align__(16) u16 Vs[2][64 * 64];
  int tid = threadIdx.x, wid = tid >> 6, lane = tid & 63;
  int r = lane & 31, hi = lane >> 5, h8 = hi * 8;
  int bh = blockIdx.x, qt = blockIdx.y;
  int b = bh >> 3, h = bh & 7;
  float ssq = 0.f, sm = 0.f;
#pragma unroll
  for (int bb2 = 0; bb2 < 16; bb2++) {
    ssq += stats[(bb2 * 8 + h) * 2];
    sm += stats[(bb2 * 8 + h) * 2 + 1];
  }
  const float NN = 16777216.0f;
  float var = (ssq - sm * sm / NN) / (NN - 1.0f);
  float sd = sqrtf(fmaxf(var, 0.0f));
  float sc = 1.4426950408889634f / (8.0f * sqrtf(1.0f + sd));
  int q0 = qt * 256 + wid * 32;  // tile1 rows; tile2 = q0 + 128
  const u16* qb = q + ((size_t)bh << 16);
  const u16* kb = k + ((size_t)bh << 16);
  const u16* vb = vt + ((size_t)bh << 16);
  const int srow = tid >> 3, scb = tid & 7;
  const u32x4 ones = {0x3F803F80u, 0x3F803F80u, 0x3F803F80u, 0x3F803F80u};

  u32x4 qf1[4], qf2[4];
#pragma unroll
  for (int tt = 0; tt < 2; tt++) {
    const u16* qrow = qb + (size_t)(q0 + tt * 128 + r) * 64 + h8;
#pragma unroll
    for (int ks = 0; ks < 4; ks++) {
      u32x4 raw = *(const u32x4*)(qrow + ks * 16);
      u32x4 w;
#pragma unroll
      for (int t = 0; t < 4; t++) {
        float lo = bf2f((u16)(raw[t] & 0xffffu)) * sc;
        float hi_ = bf2f((u16)(raw[t] >> 16)) * sc;
        w[t] = cvtpk(lo, hi_);
      }
      if (tt == 0)
        qf1[ks] = w;
      else
        qf2[ks] = w;
    }
  }

  const f32x16 zero16 = {0.f, 0.f, 0.f, 0.f, 0.f, 0.f, 0.f, 0.f,
                         0.f, 0.f, 0.f, 0.f, 0.f, 0.f, 0.f, 0.f};
  f32x16 o0 = zero16, o1 = zero16, o2 = zero16, o3 = zero16;
  f32x16 lacc1 = zero16, lacc2 = zero16;
  float m1 = -1e30f, m2 = -1e30f;

  auto stage = [&](int buf, int t0) {
#pragma unroll
    for (int i = 0; i < 2; i++) {
      int row = i * 32 + srow;
      int col = ((scb ^ (row & 7)) << 3);
      gload16(kb + (size_t)(t0 + row) * 64 + col, &Ks[buf][(i * 256 + tid) * 8]);
      gload16(vb + (size_t)row * 1024 + t0 + col, &Vs[buf][(i * 256 + tid) * 8]);
    }
  };

  stage(0, 0);
  int cur = 0;
  for (int t0 = 0; t0 < 1024; t0 += 64) {
    __syncthreads();
    if (t0 + 64 < 1024) stage(cur ^ 1, t0 + 64);
    const u16* Kc = Ks[cur];
    const u16* Vc = Vs[cur];
#pragma unroll
    for (int ss = 0; ss < 2; ss++) {
      int rk = ss * 32 + r;
      u32x4 kf[4];
#pragma unroll
      for (int ks = 0; ks < 4; ks++) {
        int cb = (ks * 2 + hi) ^ (rk & 7);
        kf[ks] = *(const u32x4*)&Kc[rk * 64 + cb * 8];
      }
      f32x16 st1 = zero16, st2 = zero16;
      __builtin_amdgcn_s_setprio(1);
#pragma unroll
      for (int ks = 0; ks < 4; ks++) st1 = mfma32(kf[ks], qf1[ks], st1);
#pragma unroll
      for (int ks = 0; ks < 4; ks++) st2 = mfma32(kf[ks], qf2[ks], st2);
      __builtin_amdgcn_s_setprio(0);
      if (ss == 1 || t0 == 0) {
        check_rescale(st1, m1, o0, o1, lacc1);
        check_rescale(st2, m2, o2, o3, lacc2);
      }
      float p1[16], p2[16];
#pragma unroll
      for (int i = 0; i < 16; i++) p1[i] = ex2(st1[i] - m1);
#pragma unroll
      for (int i = 0; i < 16; i++) p2[i] = ex2(st2[i] - m2);
      __builtin_amdgcn_s_setprio(1);
#pragma unroll
      for (int ks = 0; ks < 2; ks++) {
        u32x4 pa1 = packp(p1, ks);
        u32x4 pa2 = packp(p2, ks);
        lacc1 = mfma32(ones, pa1, lacc1);
        lacc2 = mfma32(ones, pa2, lacc2);
#pragma unroll
        for (int mt = 0; mt < 2; mt++) {
          int rv = mt * 32 + r;
          int cb = (ss * 4 + ks * 2 + hi) ^ (rv & 7);
          u32x4 vf = *(const u32x4*)&Vc[rv * 64 + cb * 8];
          if (mt == 0) {
            o0 = mfma32(vf, pa1, o0);
            o2 = mfma32(vf, pa2, o2);
          } else {
            o1 = mfma32(vf, pa1, o1);
            o3 = mfma32(vf, pa2, o3);
          }
        }
      }
      __builtin_amdgcn_s_setprio(0);
    }
    cur ^= 1;
  }

  float inv1 = 1.0f / lacc1[0];
  float inv2 = 1.0f / lacc2[0];
#pragma unroll
  for (int tt = 0; tt < 2; tt++) {
    int a_idx = q0 + tt * 128 + r;
    u16* aop = ao + ((size_t)(a_idx * 16 + b)) * 512 + h * 64;
    float inv = tt == 0 ? inv1 : inv2;
#pragma unroll
    for (int i = 0; i < 16; i++) {
      int dh0 = (i & 3) + 8 * (i >> 2) + 4 * hi;
      if (tt == 0) {
        aop[dh0] = f2bf(o0[i] * inv);
        aop[32 + dh0] = f2bf(o1[i] * inv);
      } else {
        aop[dh0] = f2bf(o2[i] * inv);
        aop[32 + dh0] = f2bf(o3[i] * inv);
      }
    }
  }
}

extern "C" void kernel_launch(void* const* d_in, const int* in_sizes, int n_in,
                              void* d_out, int out_size, void* d_ws, size_t ws_size,
                              hipStream_t stream) {
  const float* x = (const float*)d_in[0];
  const float* Wq = (const float*)d_in[1];
  const float* bq = (const float*)d_in[2];
  const float* Wk = (const float*)d_in[3];
  const float* bk = (const float*)d_in[4];
  const float* Wv = (const float*)d_in[5];
  const float* bv = (const float*)d_in[6];
  const float* g1 = (const float*)d_in[7];
  const float* be1 = (const float*)d_in[8];
  const float* g2 = (const float*)d_in[9];
  const float* be2 = (const float*)d_in[10];
  const float* W1 = (const float*)d_in[11];
  const float* bf1 = (const float*)d_in[12];
  const float* W2 = (const float*)d_in[13];
  const float* bf2v = (const float*)d_in[14];
  float* out = (float*)d_out;

  char* w = (char*)d_ws;
  size_t off = 0;
  auto alloc = [&](size_t bytes) -> void* {
    void* p = w + off;
    off += (bytes + 255) & ~(size_t)255;
    return p;
  };
  u16* xn_res = (u16*)alloc(16384ull * 512 * 2);
  u16* qbuf = (u16*)alloc(128ull * 1024 * 64 * 2);
  u16* kbuf = (u16*)alloc(128ull * 1024 * 64 * 2);
  u16* vtb = (u16*)alloc(128ull * 64 * 1024 * 2);
  u16* qtb = (u16*)alloc(128ull * 64 * 1024 * 2);
  u16* ktb = (u16*)alloc(128ull * 64 * 1024 * 2);
  u16* wqkv_t = (u16*)alloc(1536ull * 512 * 2);
  u16* w1t = (u16*)alloc(1024ull * 512 * 2);
  u16* w2t = (u16*)alloc(512ull * 1024 * 2);
  u16* h_bf = (u16*)alloc(16384ull * 1024 * 2);
  float* stats = (float*)alloc(128ull * 2 * 4);
  u16* ao_bf = (u16*)alloc(16384ull * 512 * 2);
  u16* xt_bf = (u16*)alloc(16384ull * 512 * 2);

  k_prep_ln1<<<448 + 4096, 256, 0, stream>>>(Wq, Wk, Wv, W1, W2, x, g1, be1,
                                             wqkv_t, w1t, w2t, xn_res);

  k_gemm<0, 128, 12><<<1536, 256, 0, stream>>>(
      xn_res, wqkv_t, 512, 192, bq, bk, bv, qbuf, kbuf, vtb, qtb, ktb, nullptr,
      nullptr);

  k_gram2<<<128, 256, 0, stream>>>(qtb, ktb, stats);

  k_attn<<<dim3(128, 4), 256, 0, stream>>>(qbuf, kbuf, vtb, stats, ao_bf);

  k_ln2<<<4096, 256, 0, stream>>>(xn_res, ao_bf, g2, be2, xt_bf);

  k_gemm<1, 128, 8><<<1024, 256, 0, stream>>>(
      xt_bf, w1t, 512, 128, bf1, nullptr, nullptr, h_bf, nullptr, nullptr,
      nullptr, nullptr, nullptr, nullptr);
  k_gemm<2, 64, 4><<<1024, 256, 0, stream>>>(
      h_bf, w2t, 1024, 128, bf2v, nullptr, nullptr, nullptr, nullptr, nullptr,
      nullptr, nullptr, xt_bf, out);
  (void)in_sizes; (void)n_in; (void)out_size; (void)ws_size;
}

// Round 18
// 191.451 us; speedup vs baseline: 1.1659x; 1.0307x over previous
//
#include <hip/hip_runtime.h>
#include <stdint.h>

typedef unsigned short u16;
typedef u16 u16x4 __attribute__((ext_vector_type(4)));
typedef unsigned int u32x4 __attribute__((ext_vector_type(4)));
typedef float f32x4 __attribute__((ext_vector_type(4)));
typedef float f32x16 __attribute__((ext_vector_type(16)));
typedef __bf16 bf16x8 __attribute__((ext_vector_type(8)));

#define DEVI __device__ __forceinline__

DEVI u16 f2bf(float f) {
  uint32_t u = __builtin_bit_cast(uint32_t, f);
  u = (u + 0x7FFFu + ((u >> 16) & 1u)) >> 16;
  return (u16)u;
}
DEVI float bf2f(u16 h) {
  uint32_t u = ((uint32_t)h) << 16;
  return __builtin_bit_cast(float, u);
}
DEVI f32x4 mfma16(u32x4 a, u32x4 b, f32x4 c) {
  return __builtin_amdgcn_mfma_f32_16x16x32_bf16(
      __builtin_bit_cast(bf16x8, a), __builtin_bit_cast(bf16x8, b), c, 0, 0, 0);
}
DEVI f32x16 mfma32(u32x4 a, u32x4 b, f32x16 c) {
  return __builtin_amdgcn_mfma_f32_32x32x16_bf16(
      __builtin_bit_cast(bf16x8, a), __builtin_bit_cast(bf16x8, b), c, 0, 0, 0);
}
DEVI uint32_t cvtpk(float lo, float hi) {
  uint32_t w;
  asm("v_cvt_pk_bf16_f32 %0, %1, %2" : "=v"(w) : "v"(lo), "v"(hi));
  return w;
}
DEVI void plswap(uint32_t& a, uint32_t& b) {
  asm("v_permlane32_swap_b32 %0, %1" : "+v"(a), "+v"(b));
}
DEVI float xmax2(float v) {
  uint32_t a = __builtin_bit_cast(uint32_t, v), b = a;
  plswap(a, b);
  return fmaxf(__builtin_bit_cast(float, a), __builtin_bit_cast(float, b));
}
DEVI float ex2(float x) { return __builtin_amdgcn_exp2f(x); }

#define AS1 __attribute__((address_space(1)))
#define AS3 __attribute__((address_space(3)))
DEVI void gload16(const void* g, void* l) {
  __builtin_amdgcn_global_load_lds((AS1 void*)(uintptr_t)g,
                                   (AS3 void*)(uint32_t)(uintptr_t)l, 16, 0, 0);
}

DEVI float wred(float v) {
#pragma unroll
  for (int m = 1; m < 64; m <<= 1) v += __shfl_xor(v, m);
  return v;
}

// ---------------- merged prep (5 weight transposes) + LN1 in ONE launch -------------
__global__ __launch_bounds__(256) void k_prep_ln1(
    const float* __restrict__ Wq, const float* __restrict__ Wk,
    const float* __restrict__ Wv, const float* __restrict__ W1,
    const float* __restrict__ W2, const float* __restrict__ x,
    const float* __restrict__ gam, const float* __restrict__ bet,
    u16* __restrict__ wqkv_t, u16* __restrict__ w1t, u16* __restrict__ w2t,
    u16* __restrict__ xn_res) {
  __shared__ float tile[64][65];
  int bid = blockIdx.x, tid = threadIdx.x;
  if (bid < 448) {
    const float* W;
    u16* Wt;
    int Kr, Nc, n0, k0;
    if (bid < 192) {
      int w = bid / 64, t = bid & 63;
      W = (w == 0) ? Wq : (w == 1) ? Wk : Wv;
      Wt = wqkv_t + (size_t)w * 512 * 512;
      Kr = 512; Nc = 512; n0 = (t & 7) * 64; k0 = (t >> 3) * 64;
    } else if (bid < 320) {
      int t = bid - 192;
      W = W1; Wt = w1t;
      Kr = 512; Nc = 1024; n0 = (t & 15) * 64; k0 = (t >> 4) * 64;
    } else {
      int t = bid - 320;
      W = W2; Wt = w2t;
      Kr = 1024; Nc = 512; n0 = (t & 7) * 64; k0 = (t >> 3) * 64;
    }
#pragma unroll
    for (int i = 0; i < 16; i++) {
      int idx = i * 256 + tid;
      int r = idx >> 6, cc = idx & 63;
      tile[r][cc] = W[(size_t)(k0 + r) * Nc + n0 + cc];
    }
    __syncthreads();
#pragma unroll
    for (int i = 0; i < 16; i++) {
      int idx = i * 256 + tid;
      int r = idx >> 6, cc = idx & 63;
      Wt[(size_t)(n0 + r) * Kr + k0 + cc] = f2bf(tile[cc][r]);
    }
  } else {
    int wid = tid >> 6, lane = tid & 63;
    int row = (bid - 448) * 4 + wid;
    const float* xr = x + (size_t)row * 512 + lane * 8;
    f32x4 v0 = *(const f32x4*)xr;
    f32x4 v1 = *(const f32x4*)(xr + 4);
    float s = 0.f, ss = 0.f;
#pragma unroll
    for (int j = 0; j < 4; j++) {
      s += v0[j] + v1[j];
      ss += v0[j] * v0[j] + v1[j] * v1[j];
    }
    s = wred(s);
    ss = wred(ss);
    float mean = s * (1.0f / 512.0f);
    float var = ss * (1.0f / 512.0f) - mean * mean;
    float rstd = rsqrtf(var + 1e-5f);
    const float* gp = gam + lane * 8;
    const float* bp = bet + lane * 8;
    f32x4 ga = *(const f32x4*)gp, gb = *(const f32x4*)(gp + 4);
    f32x4 ba = *(const f32x4*)bp, bb = *(const f32x4*)(bp + 4);
    u16x4 o0, o1;
#pragma unroll
    for (int j = 0; j < 4; j++) {
      o0[j] = f2bf((v0[j] - mean) * rstd * ga[j] + ba[j]);
      o1[j] = f2bf((v1[j] - mean) * rstd * gb[j] + bb[j]);
    }
    u16* pr = xn_res + (size_t)row * 512 + lane * 8;
    *(u16x4*)pr = o0;
    *(u16x4*)(pr + 4) = o1;
  }
}

// ---------------- LN2 ----------------
__global__ __launch_bounds__(256) void k_ln2(const u16* __restrict__ xn,
                                             const u16* __restrict__ ao,
                                             const float* __restrict__ gam,
                                             const float* __restrict__ bet,
                                             u16* __restrict__ xt) {
  int tid = threadIdx.x, wid = tid >> 6, lane = tid & 63;
  int row = blockIdx.x * 4 + wid;
  size_t base = (size_t)row * 512 + lane * 8;
  u16x4 a0 = *(const u16x4*)&xn[base], a1 = *(const u16x4*)&xn[base + 4];
  u16x4 c0 = *(const u16x4*)&ao[base], c1 = *(const u16x4*)&ao[base + 4];
  float v[8];
#pragma unroll
  for (int j = 0; j < 4; j++) {
    v[j] = bf2f(a0[j]) + bf2f(c0[j]);
    v[4 + j] = bf2f(a1[j]) + bf2f(c1[j]);
  }
  float s = 0.f, ss = 0.f;
#pragma unroll
  for (int j = 0; j < 8; j++) {
    s += v[j];
    ss += v[j] * v[j];
  }
  s = wred(s);
  ss = wred(ss);
  float mean = s * (1.0f / 512.0f);
  float var = ss * (1.0f / 512.0f) - mean * mean;
  float rstd = rsqrtf(var + 1e-5f);
  const float* gp = gam + lane * 8;
  const float* bp = bet + lane * 8;
  u16x4 o0, o1;
#pragma unroll
  for (int j = 0; j < 4; j++) {
    o0[j] = f2bf((v[j] - mean) * rstd * gp[j] + bp[j]);
    o1[j] = f2bf((v[4 + j] - mean) * rstd * gp[4 + j] + bp[4 + j]);
  }
  u16* pr = xt + base;
  *(u16x4*)pr = o0;
  *(u16x4*)(pr + 4) = o1;
}

// ---------------- GEMM C = A * B^T, BM x 128 tile, BK=64, 32x32 MFMA ----------------
// R14-validated main loop. EPI0 epilogue: qt/kt/vt written via LDS transpose
// (As+Bs aliased as a 128x128 bf16 C-tile after the K-loop) -> 16B coalesced
// stores instead of 8B stores at 2KB stride. Same f2bf values -> bitwise-identical.
template <int EPI, int BM, int NB>
__global__ __launch_bounds__(256, BM == 64 ? 4 : 3) void k_gemm(
    const u16* __restrict__ A, const u16* __restrict__ B, int K, int nwg8,
    const float* __restrict__ b0, const float* __restrict__ b1,
    const float* __restrict__ b2, u16* __restrict__ o0, u16* __restrict__ o1,
    u16* __restrict__ o2, u16* __restrict__ qt, u16* __restrict__ kt,
    const u16* __restrict__ resid, float* __restrict__ outf) {
  constexpr int MI = BM / 64;
  constexpr int SMEM = (EPI == 0) ? 16384 : (BM * 64 + 128 * 64);
  __shared__ __align__(16) u16 smem[SMEM];
  u16* As = smem;
  u16* Bs = smem + BM * 64;
  const int tid = threadIdx.x;
  const int wid = tid >> 6, lane = tid & 63;
  const int r31 = lane & 31, hi = lane >> 5;
  const int bid = blockIdx.x;
  const int oid = (bid & 7) * nwg8 + (bid >> 3);
  const int m0 = (oid / NB) * BM, n0 = (oid % NB) * 128;
  const int wr = (wid >> 1) * (BM / 2), wc = (wid & 1) * 64;
  const int srow = tid >> 3, scb = tid & 7;

  f32x16 acc[MI][2];
#pragma unroll
  for (int i = 0; i < MI; i++)
#pragma unroll
    for (int j = 0; j < 2; j++)
#pragma unroll
      for (int e = 0; e < 16; e++) acc[i][j][e] = 0.f;

  auto stage = [&](int k0) {
#pragma unroll
    for (int i = 0; i < BM / 32; i++) {
      int row = i * 32 + srow;
      int col = ((scb ^ (row & 7)) << 3);
      const u16* asrc;
      if constexpr (EPI == 0) {
        int m = m0 + row;  // m = b*1024+a; source row = token a*16+b
        asrc = A + ((size_t)(((m & 1023) << 4) | (m >> 10))) * K + k0 + col;
      } else {
        asrc = A + (size_t)(m0 + row) * K + k0 + col;
      }
      gload16(asrc, &As[(i * 256 + tid) * 8]);
    }
#pragma unroll
    for (int i = 0; i < 4; i++) {
      int row = i * 32 + srow;
      int col = ((scb ^ (row & 7)) << 3);
      gload16(B + (size_t)(n0 + row) * K + k0 + col, &Bs[(i * 256 + tid) * 8]);
    }
  };

  for (int k0 = 0; k0 < K; k0 += 64) {
    __syncthreads();
    stage(k0);
    __syncthreads();
#pragma unroll
    for (int kk = 0; kk < 4; kk++) {
      u32x4 af[MI], bfr[2];
#pragma unroll
      for (int mi = 0; mi < MI; mi++) {
        int row = wr + mi * 32 + r31;
        int cb = (kk * 2 + hi) ^ (row & 7);
        af[mi] = *(const u32x4*)&As[row * 64 + cb * 8];
      }
#pragma unroll
      for (int ni = 0; ni < 2; ni++) {
        int row = wc + ni * 32 + r31;
        int cb = (kk * 2 + hi) ^ (row & 7);
        bfr[ni] = *(const u32x4*)&Bs[row * 64 + cb * 8];
      }
#pragma unroll
      for (int mi = 0; mi < MI; mi++)
#pragma unroll
        for (int ni = 0; ni < 2; ni++)
          acc[mi][ni] = mfma32(af[mi], bfr[ni], acc[mi][ni]);
    }
  }

  if constexpr (EPI == 0) {
    // pass 1: row-major q/k stores (unchanged) + bias'd bf16 fragments -> LDS
    // transposed-swizzled C-tile [n_local][m_local] (smem reused after K-loop).
    __syncthreads();
#pragma unroll
    for (int mi = 0; mi < MI; mi++) {
#pragma unroll
      for (int ni = 0; ni < 2; ni++) {
        int nl = wc + ni * 32 + r31;
        int n = n0 + nl;
        int which = n >> 9, h = (n >> 6) & 7, dh = n & 63;
        const float* bp = (which == 0) ? b0 : (which == 1) ? b1 : b2;
        float bias = bp[n & 511];
#pragma unroll
        for (int grp = 0; grp < 4; grp++) {
          int ml = wr + mi * 32 + grp * 8 + hi * 4;
          u16x4 pk;
#pragma unroll
          for (int j = 0; j < 4; j++) pk[j] = f2bf(acc[mi][ni][grp * 4 + j] + bias);
          if (which < 2) {
            int mbase = m0 + ml;
            int bb2 = mbase >> 10, aa = mbase & 1023;
            int bh = bb2 * 8 + h;
            u16* dstr = ((which == 0) ? o0 : o1) + ((size_t)bh * 1024 + aa) * 64 + dh;
#pragma unroll
            for (int j = 0; j < 4; j++) dstr[(size_t)j * 64] = pk[j];
          }
          int sblk = (ml >> 3) ^ (nl & 7);
          *(u16x4*)&smem[nl * 128 + sblk * 8 + (ml & 7)] = pk;
        }
      }
    }
    __syncthreads();
    // pass 2: coalesced transposed stores (qt/kt/vt), 16B contiguous runs
    const int bb2 = m0 >> 10, aab = m0 & 1023;
#pragma unroll
    for (int s = 0; s < 8; s++) {
      int idx = s * 256 + tid;
      int nl = idx >> 4, seg = idx & 15;
      int n = n0 + nl;
      int which = n >> 9, h = (n >> 6) & 7, dh = n & 63;
      int sblk = seg ^ (nl & 7);
      u32x4 val = *(const u32x4*)&smem[nl * 128 + sblk * 8];
      u16* basep = (which == 0) ? qt : (which == 1) ? kt : o2;
      *(u32x4*)(basep + ((size_t)((bb2 * 8 + h) * 64 + dh)) * 1024 + aab + seg * 8) =
          val;
    }
  } else if constexpr (EPI == 1) {
#pragma unroll
    for (int mi = 0; mi < MI; mi++) {
#pragma unroll
      for (int ni = 0; ni < 2; ni++) {
        int n = n0 + wc + ni * 32 + r31;
        float bias = b0[n];
#pragma unroll
        for (int i = 0; i < 16; i++) {
          int m = m0 + wr + mi * 32 + (i & 3) + 8 * (i >> 2) + 4 * hi;
          float v = acc[mi][ni][i] + bias;
          v = 0.5f * v * (1.0f + erff(v * 0.70710678118654752f));
          o0[(size_t)m * 1024 + n] = f2bf(v);
        }
      }
    }
  } else {
#pragma unroll
    for (int mi = 0; mi < MI; mi++) {
#pragma unroll
      for (int ni = 0; ni < 2; ni++) {
        int n = n0 + wc + ni * 32 + r31;
        float bias = b0[n];
#pragma unroll
        for (int i = 0; i < 16; i++) {
          int m = m0 + wr + mi * 32 + (i & 3) + 8 * (i >> 2) + 4 * hi;
          float v = acc[mi][ni][i] + bias + bf2f(resid[(size_t)m * 512 + n]);
          outf[(size_t)m * 512 + n] = v;
        }
      }
    }
  }
}

// ---------------- fused MFMA gram (unchanged) ----------------
__global__ __launch_bounds__(256) void k_gram2(const u16* __restrict__ qt,
                                               const u16* __restrict__ kt,
                                               float* __restrict__ stats) {
  __shared__ __align__(16) u16 Xq[2][64 * 64];
  __shared__ __align__(16) u16 Xk[2][64 * 64];
  __shared__ float red[8];
  int tid = threadIdx.x, wid = tid >> 6, lane = tid & 63;
  int g = lane >> 4, c = lane & 15;
  int bh = blockIdx.x;
  const int srow = tid >> 3, scb = tid & 7;
  const u32x4 ones = {0x3F803F80u, 0x3F803F80u, 0x3F803F80u, 0x3F803F80u};
  const f32x4 zero = {0.f, 0.f, 0.f, 0.f};
  const u16* qsrc = qt + ((size_t)bh << 16);
  const u16* ksrc = kt + ((size_t)bh << 16);

  f32x4 gq[4], gk[4], csq = zero, csk = zero;
#pragma unroll
  for (int j = 0; j < 4; j++) {
    gq[j] = zero;
    gk[j] = zero;
  }

  auto stage = [&](int buf, int k0) {
#pragma unroll
    for (int i = 0; i < 2; i++) {
      int row = i * 32 + srow;
      int col = ((scb ^ (row & 7)) << 3);
      gload16(qsrc + (size_t)row * 1024 + k0 + col, &Xq[buf][(i * 256 + tid) * 8]);
      gload16(ksrc + (size_t)row * 1024 + k0 + col, &Xk[buf][(i * 256 + tid) * 8]);
    }
  };

  stage(0, 0);
  int cur = 0;
  for (int k0 = 0; k0 < 1024; k0 += 64) {
    __syncthreads();
    if (k0 + 64 < 1024) stage(cur ^ 1, k0 + 64);
#pragma unroll
    for (int kk = 0; kk < 2; kk++) {
      int arow = wid * 16 + c;
      int cba = (kk * 4 + g) ^ (arow & 7);
      u32x4 aq = *(const u32x4*)&Xq[cur][arow * 64 + cba * 8];
      u32x4 ak = *(const u32x4*)&Xk[cur][arow * 64 + cba * 8];
      csq = mfma16(aq, ones, csq);
      csk = mfma16(ak, ones, csk);
#pragma unroll
      for (int ni = 0; ni < 4; ni++) {
        int brow = ni * 16 + c;
        int cbb = (kk * 4 + g) ^ (brow & 7);
        u32x4 bq = *(const u32x4*)&Xq[cur][brow * 64 + cbb * 8];
        u32x4 bk = *(const u32x4*)&Xk[cur][brow * 64 + cbb * 8];
        gq[ni] = mfma16(aq, bq, gq[ni]);
        gk[ni] = mfma16(ak, bk, gk[ni]);
      }
    }
    cur ^= 1;
  }
  float part = 0.f;
#pragma unroll
  for (int ni = 0; ni < 4; ni++)
#pragma unroll
    for (int r = 0; r < 4; r++) part += gq[ni][r] * gk[ni][r];
  part = wred(part);
  float cpart = 0.f;
  if (c == 0) {
#pragma unroll
    for (int r = 0; r < 4; r++) cpart += csq[r] * csk[r];
  }
  cpart = wred(cpart);
  if (lane == 0) {
    red[wid] = part;
    red[4 + wid] = cpart;
  }
  __syncthreads();
  if (tid == 0) {
    stats[bh * 2] = red[0] + red[1] + red[2] + red[3];
    stats[bh * 2 + 1] = red[4] + red[5] + red[6] + red[7];
  }
}

// ---------------- flash attention (R14-validated) ----------------
DEVI float tilemax(const f32x16& st) {
  float m1 = fmaxf(fmaxf(st[0], st[1]), st[2]);
  float m2 = fmaxf(fmaxf(st[3], st[4]), st[5]);
  float m3 = fmaxf(fmaxf(st[6], st[7]), st[8]);
  float m4 = fmaxf(fmaxf(st[9], st[10]), st[11]);
  float m5 = fmaxf(fmaxf(st[12], st[13]), st[14]);
  float ta = fmaxf(fmaxf(m1, m2), m3);
  float tb = fmaxf(fmaxf(m4, m5), st[15]);
  return fmaxf(ta, tb);
}

DEVI void check_rescale(const f32x16& st, float& m_run, f32x16& oa, f32x16& ob,
                        f32x16& lacc) {
  float pm = xmax2(tilemax(st));
  if (__any(pm > m_run + 8.0f)) {
    float mnew = fmaxf(m_run, pm);
    float al = ex2(m_run - mnew);
    lacc[0] *= al;
#pragma unroll
    for (int i = 0; i < 16; i++) {
      oa[i] *= al;
      ob[i] *= al;
    }
    m_run = mnew;
  }
}

DEVI u32x4 packp(const float* p, int ks) {
  uint32_t A0 = cvtpk(p[ks * 8 + 0], p[ks * 8 + 1]);
  uint32_t A1 = cvtpk(p[ks * 8 + 4], p[ks * 8 + 5]);
  plswap(A0, A1);
  uint32_t B0 = cvtpk(p[ks * 8 + 2], p[ks * 8 + 3]);
  uint32_t B1 = cvtpk(p[ks * 8 + 6], p[ks * 8 + 7]);
  plswap(B0, B1);
  u32x4 pa = {A0, B0, A1, B1};
  return pa;
}

__global__ __launch_bounds__(256, 2) void k_attn(const u16* __restrict__ q,
                                                 const u16* __restrict__ k,
                                                 const u16* __restrict__ vt,
                                                 const float* __restrict__ stats,
                                                 u16* __restrict__ ao) {
  __shared__ __align__(16) u16 Ks[2][64 * 64];
  __shared__ __align__(16) u16 Vs[2][64 * 64];
  int tid = threadIdx.x, wid = tid >> 6, lane = tid & 63;
  int r = lane & 31, hi = lane >> 5, h8 = hi * 8;
  int bh = blockIdx.x, qt = blockIdx.y;
  int b = bh >> 3, h = bh & 7;
  float ssq = 0.f, sm = 0.f;
#pragma unroll
  for (int bb2 = 0; bb2 < 16; bb2++) {
    ssq += stats[(bb2 * 8 + h) * 2];
    sm += stats[(bb2 * 8 + h) * 2 + 1];
  }
  const float NN = 16777216.0f;
  float var = (ssq - sm * sm / NN) / (NN - 1.0f);
  float sd = sqrtf(fmaxf(var, 0.0f));
  float sc = 1.4426950408889634f / (8.0f * sqrtf(1.0f + sd));
  int q0 = qt * 256 + wid * 32;  // tile1 rows; tile2 = q0 + 128
  const u16* qb = q + ((size_t)bh << 16);
  const u16* kb = k + ((size_t)bh << 16);
  const u16* vb = vt + ((size_t)bh << 16);
  const int srow = tid >> 3, scb = tid & 7;
  const u32x4 ones = {0x3F803F80u, 0x3F803F80u, 0x3F803F80u, 0x3F803F80u};

  u32x4 qf1[4], qf2[4];
#pragma unroll
  for (int tt = 0; tt < 2; tt++) {
    const u16* qrow = qb + (size_t)(q0 + tt * 128 + r) * 64 + h8;
#pragma unroll
    for (int ks = 0; ks < 4; ks++) {
      u32x4 raw = *(const u32x4*)(qrow + ks * 16);
      u32x4 w;
#pragma unroll
      for (int t = 0; t < 4; t++) {
        float lo = bf2f((u16)(raw[t] & 0xffffu)) * sc;
        float hi_ = bf2f((u16)(raw[t] >> 16)) * sc;
        w[t] = cvtpk(lo, hi_);
      }
      if (tt == 0)
        qf1[ks] = w;
      else
        qf2[ks] = w;
    }
  }

  const f32x16 zero16 = {0.f, 0.f, 0.f, 0.f, 0.f, 0.f, 0.f, 0.f,
                         0.f, 0.f, 0.f, 0.f, 0.f, 0.f, 0.f, 0.f};
  f32x16 o0 = zero16, o1 = zero16, o2 = zero16, o3 = zero16;
  f32x16 lacc1 = zero16, lacc2 = zero16;
  float m1 = -1e30f, m2 = -1e30f;

  auto stage = [&](int buf, int t0) {
#pragma unroll
    for (int i = 0; i < 2; i++) {
      int row = i * 32 + srow;
      int col = ((scb ^ (row & 7)) << 3);
      gload16(kb + (size_t)(t0 + row) * 64 + col, &Ks[buf][(i * 256 + tid) * 8]);
      gload16(vb + (size_t)row * 1024 + t0 + col, &Vs[buf][(i * 256 + tid) * 8]);
    }
  };

  stage(0, 0);
  int cur = 0;
  for (int t0 = 0; t0 < 1024; t0 += 64) {
    __syncthreads();
    if (t0 + 64 < 1024) stage(cur ^ 1, t0 + 64);
    const u16* Kc = Ks[cur];
    const u16* Vc = Vs[cur];
#pragma unroll
    for (int ss = 0; ss < 2; ss++) {
      int rk = ss * 32 + r;
      u32x4 kf[4];
#pragma unroll
      for (int ks = 0; ks < 4; ks++) {
        int cb = (ks * 2 + hi) ^ (rk & 7);
        kf[ks] = *(const u32x4*)&Kc[rk * 64 + cb * 8];
      }
      f32x16 st1 = zero16, st2 = zero16;
      __builtin_amdgcn_s_setprio(1);
#pragma unroll
      for (int ks = 0; ks < 4; ks++) st1 = mfma32(kf[ks], qf1[ks], st1);
#pragma unroll
      for (int ks = 0; ks < 4; ks++) st2 = mfma32(kf[ks], qf2[ks], st2);
      __builtin_amdgcn_s_setprio(0);
      if (ss == 1 || t0 == 0) {
        check_rescale(st1, m1, o0, o1, lacc1);
        check_rescale(st2, m2, o2, o3, lacc2);
      }
      float p1[16], p2[16];
#pragma unroll
      for (int i = 0; i < 16; i++) p1[i] = ex2(st1[i] - m1);
#pragma unroll
      for (int i = 0; i < 16; i++) p2[i] = ex2(st2[i] - m2);
      __builtin_amdgcn_s_setprio(1);
#pragma unroll
      for (int ks = 0; ks < 2; ks++) {
        u32x4 pa1 = packp(p1, ks);
        u32x4 pa2 = packp(p2, ks);
        lacc1 = mfma32(ones, pa1, lacc1);
        lacc2 = mfma32(ones, pa2, lacc2);
#pragma unroll
        for (int mt = 0; mt < 2; mt++) {
          int rv = mt * 32 + r;
          int cb = (ss * 4 + ks * 2 + hi) ^ (rv & 7);
          u32x4 vf = *(const u32x4*)&Vc[rv * 64 + cb * 8];
          if (mt == 0) {
            o0 = mfma32(vf, pa1, o0);
            o2 = mfma32(vf, pa2, o2);
          } else {
            o1 = mfma32(vf, pa1, o1);
            o3 = mfma32(vf, pa2, o3);
          }
        }
      }
      __builtin_amdgcn_s_setprio(0);
    }
    cur ^= 1;
  }

  float inv1 = 1.0f / lacc1[0];
  float inv2 = 1.0f / lacc2[0];
#pragma unroll
  for (int tt = 0; tt < 2; tt++) {
    int a_idx = q0 + tt * 128 + r;
    u16* aop = ao + ((size_t)(a_idx * 16 + b)) * 512 + h * 64;
    float inv = tt == 0 ? inv1 : inv2;
#pragma unroll
    for (int i = 0; i < 16; i++) {
      int dh0 = (i & 3) + 8 * (i >> 2) + 4 * hi;
      if (tt == 0) {
        aop[dh0] = f2bf(o0[i] * inv);
        aop[32 + dh0] = f2bf(o1[i] * inv);
      } else {
        aop[dh0] = f2bf(o2[i] * inv);
        aop[32 + dh0] = f2bf(o3[i] * inv);
      }
    }
  }
}

extern "C" void kernel_launch(void* const* d_in, const int* in_sizes, int n_in,
                              void* d_out, int out_size, void* d_ws, size_t ws_size,
                              hipStream_t stream) {
  const float* x = (const float*)d_in[0];
  const float* Wq = (const float*)d_in[1];
  const float* bq = (const float*)d_in[2];
  const float* Wk = (const float*)d_in[3];
  const float* bk = (const float*)d_in[4];
  const float* Wv = (const float*)d_in[5];
  const float* bv = (const float*)d_in[6];
  const float* g1 = (const float*)d_in[7];
  const float* be1 = (const float*)d_in[8];
  const float* g2 = (const float*)d_in[9];
  const float* be2 = (const float*)d_in[10];
  const float* W1 = (const float*)d_in[11];
  const float* bf1 = (const float*)d_in[12];
  const float* W2 = (const float*)d_in[13];
  const float* bf2v = (const float*)d_in[14];
  float* out = (float*)d_out;

  char* w = (char*)d_ws;
  size_t off = 0;
  auto alloc = [&](size_t bytes) -> void* {
    void* p = w + off;
    off += (bytes + 255) & ~(size_t)255;
    return p;
  };
  u16* xn_res = (u16*)alloc(16384ull * 512 * 2);
  u16* qbuf = (u16*)alloc(128ull * 1024 * 64 * 2);
  u16* kbuf = (u16*)alloc(128ull * 1024 * 64 * 2);
  u16* vtb = (u16*)alloc(128ull * 64 * 1024 * 2);
  u16* qtb = (u16*)alloc(128ull * 64 * 1024 * 2);
  u16* ktb = (u16*)alloc(128ull * 64 * 1024 * 2);
  u16* wqkv_t = (u16*)alloc(1536ull * 512 * 2);
  u16* w1t = (u16*)alloc(1024ull * 512 * 2);
  u16* w2t = (u16*)alloc(512ull * 1024 * 2);
  u16* h_bf = (u16*)alloc(16384ull * 1024 * 2);
  float* stats = (float*)alloc(128ull * 2 * 4);
  u16* ao_bf = (u16*)alloc(16384ull * 512 * 2);
  u16* xt_bf = (u16*)alloc(16384ull * 512 * 2);

  k_prep_ln1<<<448 + 4096, 256, 0, stream>>>(Wq, Wk, Wv, W1, W2, x, g1, be1,
                                             wqkv_t, w1t, w2t, xn_res);

  k_gemm<0, 128, 12><<<1536, 256, 0, stream>>>(
      xn_res, wqkv_t, 512, 192, bq, bk, bv, qbuf, kbuf, vtb, qtb, ktb, nullptr,
      nullptr);

  k_gram2<<<128, 256, 0, stream>>>(qtb, ktb, stats);

  k_attn<<<dim3(128, 4), 256, 0, stream>>>(qbuf, kbuf, vtb, stats, ao_bf);

  k_ln2<<<4096, 256, 0, stream>>>(xn_res, ao_bf, g2, be2, xt_bf);

  k_gemm<1, 128, 8><<<1024, 256, 0, stream>>>(
      xt_bf, w1t, 512, 128, bf1, nullptr, nullptr, h_bf, nullptr, nullptr,
      nullptr, nullptr, nullptr, nullptr);
  k_gemm<2, 64, 4><<<1024, 256, 0, stream>>>(
      h_bf, w2t, 1024, 128, bf2v, nullptr, nullptr, nullptr, nullptr, nullptr,
      nullptr, nullptr, xt_bf, out);
  (void)in_sizes; (void)n_in; (void)out_size; (void)ws_size;
}

// Round 19
// 191.125 us; speedup vs baseline: 1.1678x; 1.0017x over previous
//
#include <hip/hip_runtime.h>
#include <stdint.h>

typedef unsigned short u16;
typedef u16 u16x4 __attribute__((ext_vector_type(4)));
typedef unsigned int u32x4 __attribute__((ext_vector_type(4)));
typedef float f32x4 __attribute__((ext_vector_type(4)));
typedef float f32x16 __attribute__((ext_vector_type(16)));
typedef __bf16 bf16x8 __attribute__((ext_vector_type(8)));

#define DEVI __device__ __forceinline__

DEVI u16 f2bf(float f) {
  uint32_t u = __builtin_bit_cast(uint32_t, f);
  u = (u + 0x7FFFu + ((u >> 16) & 1u)) >> 16;
  return (u16)u;
}
DEVI float bf2f(u16 h) {
  uint32_t u = ((uint32_t)h) << 16;
  return __builtin_bit_cast(float, u);
}
DEVI f32x4 mfma16(u32x4 a, u32x4 b, f32x4 c) {
  return __builtin_amdgcn_mfma_f32_16x16x32_bf16(
      __builtin_bit_cast(bf16x8, a), __builtin_bit_cast(bf16x8, b), c, 0, 0, 0);
}
DEVI f32x16 mfma32(u32x4 a, u32x4 b, f32x16 c) {
  return __builtin_amdgcn_mfma_f32_32x32x16_bf16(
      __builtin_bit_cast(bf16x8, a), __builtin_bit_cast(bf16x8, b), c, 0, 0, 0);
}
DEVI uint32_t cvtpk(float lo, float hi) {
  uint32_t w;
  asm("v_cvt_pk_bf16_f32 %0, %1, %2" : "=v"(w) : "v"(lo), "v"(hi));
  return w;
}
DEVI void plswap(uint32_t& a, uint32_t& b) {
  asm("v_permlane32_swap_b32 %0, %1" : "+v"(a), "+v"(b));
}
DEVI float xmax2(float v) {
  uint32_t a = __builtin_bit_cast(uint32_t, v), b = a;
  plswap(a, b);
  return fmaxf(__builtin_bit_cast(float, a), __builtin_bit_cast(float, b));
}
DEVI float ex2(float x) { return __builtin_amdgcn_exp2f(x); }

#define AS1 __attribute__((address_space(1)))
#define AS3 __attribute__((address_space(3)))
DEVI void gload16(const void* g, void* l) {
  __builtin_amdgcn_global_load_lds((AS1 void*)(uintptr_t)g,
                                   (AS3 void*)(uint32_t)(uintptr_t)l, 16, 0, 0);
}

DEVI float wred(float v) {
#pragma unroll
  for (int m = 1; m < 64; m <<= 1) v += __shfl_xor(v, m);
  return v;
}

// ---------------- merged prep (5 weight transposes) + LN1 in ONE launch -------------
__global__ __launch_bounds__(256) void k_prep_ln1(
    const float* __restrict__ Wq, const float* __restrict__ Wk,
    const float* __restrict__ Wv, const float* __restrict__ W1,
    const float* __restrict__ W2, const float* __restrict__ x,
    const float* __restrict__ gam, const float* __restrict__ bet,
    u16* __restrict__ wqkv_t, u16* __restrict__ w1t, u16* __restrict__ w2t,
    u16* __restrict__ xn_res) {
  __shared__ float tile[64][65];
  int bid = blockIdx.x, tid = threadIdx.x;
  if (bid < 448) {
    const float* W;
    u16* Wt;
    int Kr, Nc, n0, k0;
    if (bid < 192) {
      int w = bid / 64, t = bid & 63;
      W = (w == 0) ? Wq : (w == 1) ? Wk : Wv;
      Wt = wqkv_t + (size_t)w * 512 * 512;
      Kr = 512; Nc = 512; n0 = (t & 7) * 64; k0 = (t >> 3) * 64;
    } else if (bid < 320) {
      int t = bid - 192;
      W = W1; Wt = w1t;
      Kr = 512; Nc = 1024; n0 = (t & 15) * 64; k0 = (t >> 4) * 64;
    } else {
      int t = bid - 320;
      W = W2; Wt = w2t;
      Kr = 1024; Nc = 512; n0 = (t & 7) * 64; k0 = (t >> 3) * 64;
    }
#pragma unroll
    for (int i = 0; i < 16; i++) {
      int idx = i * 256 + tid;
      int r = idx >> 6, cc = idx & 63;
      tile[r][cc] = W[(size_t)(k0 + r) * Nc + n0 + cc];
    }
    __syncthreads();
#pragma unroll
    for (int i = 0; i < 16; i++) {
      int idx = i * 256 + tid;
      int r = idx >> 6, cc = idx & 63;
      Wt[(size_t)(n0 + r) * Kr + k0 + cc] = f2bf(tile[cc][r]);
    }
  } else {
    int wid = tid >> 6, lane = tid & 63;
    int row = (bid - 448) * 4 + wid;
    const float* xr = x + (size_t)row * 512 + lane * 8;
    f32x4 v0 = *(const f32x4*)xr;
    f32x4 v1 = *(const f32x4*)(xr + 4);
    float s = 0.f, ss = 0.f;
#pragma unroll
    for (int j = 0; j < 4; j++) {
      s += v0[j] + v1[j];
      ss += v0[j] * v0[j] + v1[j] * v1[j];
    }
    s = wred(s);
    ss = wred(ss);
    float mean = s * (1.0f / 512.0f);
    float var = ss * (1.0f / 512.0f) - mean * mean;
    float rstd = rsqrtf(var + 1e-5f);
    const float* gp = gam + lane * 8;
    const float* bp = bet + lane * 8;
    f32x4 ga = *(const f32x4*)gp, gb = *(const f32x4*)(gp + 4);
    f32x4 ba = *(const f32x4*)bp, bb = *(const f32x4*)(bp + 4);
    u16x4 o0, o1;
#pragma unroll
    for (int j = 0; j < 4; j++) {
      o0[j] = f2bf((v0[j] - mean) * rstd * ga[j] + ba[j]);
      o1[j] = f2bf((v1[j] - mean) * rstd * gb[j] + bb[j]);
    }
    u16* pr = xn_res + (size_t)row * 512 + lane * 8;
    *(u16x4*)pr = o0;
    *(u16x4*)(pr + 4) = o1;
  }
}

// ---------------- LN2 ----------------
__global__ __launch_bounds__(256) void k_ln2(const u16* __restrict__ xn,
                                             const u16* __restrict__ ao,
                                             const float* __restrict__ gam,
                                             const float* __restrict__ bet,
                                             u16* __restrict__ xt) {
  int tid = threadIdx.x, wid = tid >> 6, lane = tid & 63;
  int row = blockIdx.x * 4 + wid;
  size_t base = (size_t)row * 512 + lane * 8;
  u16x4 a0 = *(const u16x4*)&xn[base], a1 = *(const u16x4*)&xn[base + 4];
  u16x4 c0 = *(const u16x4*)&ao[base], c1 = *(const u16x4*)&ao[base + 4];
  float v[8];
#pragma unroll
  for (int j = 0; j < 4; j++) {
    v[j] = bf2f(a0[j]) + bf2f(c0[j]);
    v[4 + j] = bf2f(a1[j]) + bf2f(c1[j]);
  }
  float s = 0.f, ss = 0.f;
#pragma unroll
  for (int j = 0; j < 8; j++) {
    s += v[j];
    ss += v[j] * v[j];
  }
  s = wred(s);
  ss = wred(ss);
  float mean = s * (1.0f / 512.0f);
  float var = ss * (1.0f / 512.0f) - mean * mean;
  float rstd = rsqrtf(var + 1e-5f);
  const float* gp = gam + lane * 8;
  const float* bp = bet + lane * 8;
  u16x4 o0, o1;
#pragma unroll
  for (int j = 0; j < 4; j++) {
    o0[j] = f2bf((v[j] - mean) * rstd * gp[j] + bp[j]);
    o1[j] = f2bf((v[4 + j] - mean) * rstd * gp[4 + j] + bp[4 + j]);
  }
  u16* pr = xt + base;
  *(u16x4*)pr = o0;
  *(u16x4*)(pr + 4) = o1;
}

// ---------------- GEMM C = A * B^T, BM x 128 tile, BK=64, 32x32 MFMA ----------------
// R18-validated: main loop + LDS-transpose EPI0 epilogue (coalesced qt/kt/vt).
template <int EPI, int BM, int NB>
__global__ __launch_bounds__(256, BM == 64 ? 4 : 3) void k_gemm(
    const u16* __restrict__ A, const u16* __restrict__ B, int K, int nwg8,
    const float* __restrict__ b0, const float* __restrict__ b1,
    const float* __restrict__ b2, u16* __restrict__ o0, u16* __restrict__ o1,
    u16* __restrict__ o2, u16* __restrict__ qt, u16* __restrict__ kt,
    const u16* __restrict__ resid, float* __restrict__ outf) {
  constexpr int MI = BM / 64;
  constexpr int SMEM = (EPI == 0) ? 16384 : (BM * 64 + 128 * 64);
  __shared__ __align__(16) u16 smem[SMEM];
  u16* As = smem;
  u16* Bs = smem + BM * 64;
  const int tid = threadIdx.x;
  const int wid = tid >> 6, lane = tid & 63;
  const int r31 = lane & 31, hi = lane >> 5;
  const int bid = blockIdx.x;
  const int oid = (bid & 7) * nwg8 + (bid >> 3);
  const int m0 = (oid / NB) * BM, n0 = (oid % NB) * 128;
  const int wr = (wid >> 1) * (BM / 2), wc = (wid & 1) * 64;
  const int srow = tid >> 3, scb = tid & 7;

  f32x16 acc[MI][2];
#pragma unroll
  for (int i = 0; i < MI; i++)
#pragma unroll
    for (int j = 0; j < 2; j++)
#pragma unroll
      for (int e = 0; e < 16; e++) acc[i][j][e] = 0.f;

  auto stage = [&](int k0) {
#pragma unroll
    for (int i = 0; i < BM / 32; i++) {
      int row = i * 32 + srow;
      int col = ((scb ^ (row & 7)) << 3);
      const u16* asrc;
      if constexpr (EPI == 0) {
        int m = m0 + row;  // m = b*1024+a; source row = token a*16+b
        asrc = A + ((size_t)(((m & 1023) << 4) | (m >> 10))) * K + k0 + col;
      } else {
        asrc = A + (size_t)(m0 + row) * K + k0 + col;
      }
      gload16(asrc, &As[(i * 256 + tid) * 8]);
    }
#pragma unroll
    for (int i = 0; i < 4; i++) {
      int row = i * 32 + srow;
      int col = ((scb ^ (row & 7)) << 3);
      gload16(B + (size_t)(n0 + row) * K + k0 + col, &Bs[(i * 256 + tid) * 8]);
    }
  };

  for (int k0 = 0; k0 < K; k0 += 64) {
    __syncthreads();
    stage(k0);
    __syncthreads();
#pragma unroll
    for (int kk = 0; kk < 4; kk++) {
      u32x4 af[MI], bfr[2];
#pragma unroll
      for (int mi = 0; mi < MI; mi++) {
        int row = wr + mi * 32 + r31;
        int cb = (kk * 2 + hi) ^ (row & 7);
        af[mi] = *(const u32x4*)&As[row * 64 + cb * 8];
      }
#pragma unroll
      for (int ni = 0; ni < 2; ni++) {
        int row = wc + ni * 32 + r31;
        int cb = (kk * 2 + hi) ^ (row & 7);
        bfr[ni] = *(const u32x4*)&Bs[row * 64 + cb * 8];
      }
#pragma unroll
      for (int mi = 0; mi < MI; mi++)
#pragma unroll
        for (int ni = 0; ni < 2; ni++)
          acc[mi][ni] = mfma32(af[mi], bfr[ni], acc[mi][ni]);
    }
  }

  if constexpr (EPI == 0) {
    __syncthreads();
#pragma unroll
    for (int mi = 0; mi < MI; mi++) {
#pragma unroll
      for (int ni = 0; ni < 2; ni++) {
        int nl = wc + ni * 32 + r31;
        int n = n0 + nl;
        int which = n >> 9, h = (n >> 6) & 7, dh = n & 63;
        const float* bp = (which == 0) ? b0 : (which == 1) ? b1 : b2;
        float bias = bp[n & 511];
#pragma unroll
        for (int grp = 0; grp < 4; grp++) {
          int ml = wr + mi * 32 + grp * 8 + hi * 4;
          u16x4 pk;
#pragma unroll
          for (int j = 0; j < 4; j++) pk[j] = f2bf(acc[mi][ni][grp * 4 + j] + bias);
          if (which < 2) {
            int mbase = m0 + ml;
            int bb2 = mbase >> 10, aa = mbase & 1023;
            int bh = bb2 * 8 + h;
            u16* dstr = ((which == 0) ? o0 : o1) + ((size_t)bh * 1024 + aa) * 64 + dh;
#pragma unroll
            for (int j = 0; j < 4; j++) dstr[(size_t)j * 64] = pk[j];
          }
          int sblk = (ml >> 3) ^ (nl & 7);
          *(u16x4*)&smem[nl * 128 + sblk * 8 + (ml & 7)] = pk;
        }
      }
    }
    __syncthreads();
    const int bb2 = m0 >> 10, aab = m0 & 1023;
#pragma unroll
    for (int s = 0; s < 8; s++) {
      int idx = s * 256 + tid;
      int nl = idx >> 4, seg = idx & 15;
      int n = n0 + nl;
      int which = n >> 9, h = (n >> 6) & 7, dh = n & 63;
      int sblk = seg ^ (nl & 7);
      u32x4 val = *(const u32x4*)&smem[nl * 128 + sblk * 8];
      u16* basep = (which == 0) ? qt : (which == 1) ? kt : o2;
      *(u32x4*)(basep + ((size_t)((bb2 * 8 + h) * 64 + dh)) * 1024 + aab + seg * 8) =
          val;
    }
  } else if constexpr (EPI == 1) {
#pragma unroll
    for (int mi = 0; mi < MI; mi++) {
#pragma unroll
      for (int ni = 0; ni < 2; ni++) {
        int n = n0 + wc + ni * 32 + r31;
        float bias = b0[n];
#pragma unroll
        for (int i = 0; i < 16; i++) {
          int m = m0 + wr + mi * 32 + (i & 3) + 8 * (i >> 2) + 4 * hi;
          float v = acc[mi][ni][i] + bias;
          v = 0.5f * v * (1.0f + erff(v * 0.70710678118654752f));
          o0[(size_t)m * 1024 + n] = f2bf(v);
        }
      }
    }
  } else {
#pragma unroll
    for (int mi = 0; mi < MI; mi++) {
#pragma unroll
      for (int ni = 0; ni < 2; ni++) {
        int n = n0 + wc + ni * 32 + r31;
        float bias = b0[n];
#pragma unroll
        for (int i = 0; i < 16; i++) {
          int m = m0 + wr + mi * 32 + (i & 3) + 8 * (i >> 2) + 4 * hi;
          float v = acc[mi][ni][i] + bias + bf2f(resid[(size_t)m * 512 + n]);
          outf[(size_t)m * 512 + n] = v;
        }
      }
    }
  }
}

// ---------------- fused MFMA gram: K-range split across 2 blocks per bh -------------
// grid (128 bh, 2 halves); each block covers 512 of the 1024 a-columns. Partial
// (ssq, colsum-dot) per half -> stats[bh*4 + half*2 + {0,1}]; summed in k_attn.
__global__ __launch_bounds__(256) void k_gram2(const u16* __restrict__ qt,
                                               const u16* __restrict__ kt,
                                               float* __restrict__ stats) {
  __shared__ __align__(16) u16 Xq[2][64 * 64];
  __shared__ __align__(16) u16 Xk[2][64 * 64];
  __shared__ float red[8];
  int tid = threadIdx.x, wid = tid >> 6, lane = tid & 63;
  int g = lane >> 4, c = lane & 15;
  int bh = blockIdx.x, half = blockIdx.y;
  const int kbase = half * 512;
  const int srow = tid >> 3, scb = tid & 7;
  const u32x4 ones = {0x3F803F80u, 0x3F803F80u, 0x3F803F80u, 0x3F803F80u};
  const f32x4 zero = {0.f, 0.f, 0.f, 0.f};
  const u16* qsrc = qt + ((size_t)bh << 16);
  const u16* ksrc = kt + ((size_t)bh << 16);

  f32x4 gq[4], gk[4], csq = zero, csk = zero;
#pragma unroll
  for (int j = 0; j < 4; j++) {
    gq[j] = zero;
    gk[j] = zero;
  }

  auto stage = [&](int buf, int k0) {
#pragma unroll
    for (int i = 0; i < 2; i++) {
      int row = i * 32 + srow;
      int col = ((scb ^ (row & 7)) << 3);
      gload16(qsrc + (size_t)row * 1024 + k0 + col, &Xq[buf][(i * 256 + tid) * 8]);
      gload16(ksrc + (size_t)row * 1024 + k0 + col, &Xk[buf][(i * 256 + tid) * 8]);
    }
  };

  stage(0, kbase);
  int cur = 0;
  for (int k0 = kbase; k0 < kbase + 512; k0 += 64) {
    __syncthreads();
    if (k0 + 64 < kbase + 512) stage(cur ^ 1, k0 + 64);
#pragma unroll
    for (int kk = 0; kk < 2; kk++) {
      int arow = wid * 16 + c;
      int cba = (kk * 4 + g) ^ (arow & 7);
      u32x4 aq = *(const u32x4*)&Xq[cur][arow * 64 + cba * 8];
      u32x4 ak = *(const u32x4*)&Xk[cur][arow * 64 + cba * 8];
      csq = mfma16(aq, ones, csq);
      csk = mfma16(ak, ones, csk);
#pragma unroll
      for (int ni = 0; ni < 4; ni++) {
        int brow = ni * 16 + c;
        int cbb = (kk * 4 + g) ^ (brow & 7);
        u32x4 bq = *(const u32x4*)&Xq[cur][brow * 64 + cbb * 8];
        u32x4 bk = *(const u32x4*)&Xk[cur][brow * 64 + cbb * 8];
        gq[ni] = mfma16(aq, bq, gq[ni]);
        gk[ni] = mfma16(ak, bk, gk[ni]);
      }
    }
    cur ^= 1;
  }
  float part = 0.f;
#pragma unroll
  for (int ni = 0; ni < 4; ni++)
#pragma unroll
    for (int r = 0; r < 4; r++) part += gq[ni][r] * gk[ni][r];
  part = wred(part);
  float cpart = 0.f;
  if (c == 0) {
#pragma unroll
    for (int r = 0; r < 4; r++) cpart += csq[r] * csk[r];
  }
  cpart = wred(cpart);
  if (lane == 0) {
    red[wid] = part;
    red[4 + wid] = cpart;
  }
  __syncthreads();
  if (tid == 0) {
    stats[bh * 4 + half * 2] = red[0] + red[1] + red[2] + red[3];
    stats[bh * 4 + half * 2 + 1] = red[4] + red[5] + red[6] + red[7];
  }
}

// ---------------- flash attention (R14-validated; stats now 4-wide per bh) ----------
DEVI float tilemax(const f32x16& st) {
  float m1 = fmaxf(fmaxf(st[0], st[1]), st[2]);
  float m2 = fmaxf(fmaxf(st[3], st[4]), st[5]);
  float m3 = fmaxf(fmaxf(st[6], st[7]), st[8]);
  float m4 = fmaxf(fmaxf(st[9], st[10]), st[11]);
  float m5 = fmaxf(fmaxf(st[12], st[13]), st[14]);
  float ta = fmaxf(fmaxf(m1, m2), m3);
  float tb = fmaxf(fmaxf(m4, m5), st[15]);
  return fmaxf(ta, tb);
}

DEVI void check_rescale(const f32x16& st, float& m_run, f32x16& oa, f32x16& ob,
                        f32x16& lacc) {
  float pm = xmax2(tilemax(st));
  if (__any(pm > m_run + 8.0f)) {
    float mnew = fmaxf(m_run, pm);
    float al = ex2(m_run - mnew);
    lacc[0] *= al;
#pragma unroll
    for (int i = 0; i < 16; i++) {
      oa[i] *= al;
      ob[i] *= al;
    }
    m_run = mnew;
  }
}

DEVI u32x4 packp(const float* p, int ks) {
  uint32_t A0 = cvtpk(p[ks * 8 + 0], p[ks * 8 + 1]);
  uint32_t A1 = cvtpk(p[ks * 8 + 4], p[ks * 8 + 5]);
  plswap(A0, A1);
  uint32_t B0 = cvtpk(p[ks * 8 + 2], p[ks * 8 + 3]);
  uint32_t B1 = cvtpk(p[ks * 8 + 6], p[ks * 8 + 7]);
  plswap(B0, B1);
  u32x4 pa = {A0, B0, A1, B1};
  return pa;
}

__global__ __launch_bounds__(256, 2) void k_attn(const u16* __restrict__ q,
                                                 const u16* __restrict__ k,
                                                 const u16* __restrict__ vt,
                                                 const float* __restrict__ stats,
                                                 u16* __restrict__ ao) {
  __shared__ __align__(16) u16 Ks[2][64 * 64];
  __shared__ __align__(16) u16 Vs[2][64 * 64];
  int tid = threadIdx.x, wid = tid >> 6, lane = tid & 63;
  int r = lane & 31, hi = lane >> 5, h8 = hi * 8;
  int bh = blockIdx.x, qt = blockIdx.y;
  int b = bh >> 3, h = bh & 7;
  float ssq = 0.f, sm = 0.f;
#pragma unroll
  for (int bb2 = 0; bb2 < 16; bb2++) {
    int base = (bb2 * 8 + h) * 4;
    ssq += stats[base] + stats[base + 2];
    sm += stats[base + 1] + stats[base + 3];
  }
  const float NN = 16777216.0f;
  float var = (ssq - sm * sm / NN) / (NN - 1.0f);
  float sd = sqrtf(fmaxf(var, 0.0f));
  float sc = 1.4426950408889634f / (8.0f * sqrtf(1.0f + sd));
  int q0 = qt * 256 + wid * 32;  // tile1 rows; tile2 = q0 + 128
  const u16* qb = q + ((size_t)bh << 16);
  const u16* kb = k + ((size_t)bh << 16);
  const u16* vb = vt + ((size_t)bh << 16);
  const int srow = tid >> 3, scb = tid & 7;
  const u32x4 ones = {0x3F803F80u, 0x3F803F80u, 0x3F803F80u, 0x3F803F80u};

  u32x4 qf1[4], qf2[4];
#pragma unroll
  for (int tt = 0; tt < 2; tt++) {
    const u16* qrow = qb + (size_t)(q0 + tt * 128 + r) * 64 + h8;
#pragma unroll
    for (int ks = 0; ks < 4; ks++) {
      u32x4 raw = *(const u32x4*)(qrow + ks * 16);
      u32x4 w;
#pragma unroll
      for (int t = 0; t < 4; t++) {
        float lo = bf2f((u16)(raw[t] & 0xffffu)) * sc;
        float hi_ = bf2f((u16)(raw[t] >> 16)) * sc;
        w[t] = cvtpk(lo, hi_);
      }
      if (tt == 0)
        qf1[ks] = w;
      else
        qf2[ks] = w;
    }
  }

  const f32x16 zero16 = {0.f, 0.f, 0.f, 0.f, 0.f, 0.f, 0.f, 0.f,
                         0.f, 0.f, 0.f, 0.f, 0.f, 0.f, 0.f, 0.f};
  f32x16 o0 = zero16, o1 = zero16, o2 = zero16, o3 = zero16;
  f32x16 lacc1 = zero16, lacc2 = zero16;
  float m1 = -1e30f, m2 = -1e30f;

  auto stage = [&](int buf, int t0) {
#pragma unroll
    for (int i = 0; i < 2; i++) {
      int row = i * 32 + srow;
      int col = ((scb ^ (row & 7)) << 3);
      gload16(kb + (size_t)(t0 + row) * 64 + col, &Ks[buf][(i * 256 + tid) * 8]);
      gload16(vb + (size_t)row * 1024 + t0 + col, &Vs[buf][(i * 256 + tid) * 8]);
    }
  };

  stage(0, 0);
  int cur = 0;
  for (int t0 = 0; t0 < 1024; t0 += 64) {
    __syncthreads();
    if (t0 + 64 < 1024) stage(cur ^ 1, t0 + 64);
    const u16* Kc = Ks[cur];
    const u16* Vc = Vs[cur];
#pragma unroll
    for (int ss = 0; ss < 2; ss++) {
      int rk = ss * 32 + r;
      u32x4 kf[4];
#pragma unroll
      for (int ks = 0; ks < 4; ks++) {
        int cb = (ks * 2 + hi) ^ (rk & 7);
        kf[ks] = *(const u32x4*)&Kc[rk * 64 + cb * 8];
      }
      f32x16 st1 = zero16, st2 = zero16;
      __builtin_amdgcn_s_setprio(1);
#pragma unroll
      for (int ks = 0; ks < 4; ks++) st1 = mfma32(kf[ks], qf1[ks], st1);
#pragma unroll
      for (int ks = 0; ks < 4; ks++) st2 = mfma32(kf[ks], qf2[ks], st2);
      __builtin_amdgcn_s_setprio(0);
      if (ss == 1 || t0 == 0) {
        check_rescale(st1, m1, o0, o1, lacc1);
        check_rescale(st2, m2, o2, o3, lacc2);
      }
      float p1[16], p2[16];
#pragma unroll
      for (int i = 0; i < 16; i++) p1[i] = ex2(st1[i] - m1);
#pragma unroll
      for (int i = 0; i < 16; i++) p2[i] = ex2(st2[i] - m2);
      __builtin_amdgcn_s_setprio(1);
#pragma unroll
      for (int ks = 0; ks < 2; ks++) {
        u32x4 pa1 = packp(p1, ks);
        u32x4 pa2 = packp(p2, ks);
        lacc1 = mfma32(ones, pa1, lacc1);
        lacc2 = mfma32(ones, pa2, lacc2);
#pragma unroll
        for (int mt = 0; mt < 2; mt++) {
          int rv = mt * 32 + r;
          int cb = (ss * 4 + ks * 2 + hi) ^ (rv & 7);
          u32x4 vf = *(const u32x4*)&Vc[rv * 64 + cb * 8];
          if (mt == 0) {
            o0 = mfma32(vf, pa1, o0);
            o2 = mfma32(vf, pa2, o2);
          } else {
            o1 = mfma32(vf, pa1, o1);
            o3 = mfma32(vf, pa2, o3);
          }
        }
      }
      __builtin_amdgcn_s_setprio(0);
    }
    cur ^= 1;
  }

  float inv1 = 1.0f / lacc1[0];
  float inv2 = 1.0f / lacc2[0];
#pragma unroll
  for (int tt = 0; tt < 2; tt++) {
    int a_idx = q0 + tt * 128 + r;
    u16* aop = ao + ((size_t)(a_idx * 16 + b)) * 512 + h * 64;
    float inv = tt == 0 ? inv1 : inv2;
#pragma unroll
    for (int i = 0; i < 16; i++) {
      int dh0 = (i & 3) + 8 * (i >> 2) + 4 * hi;
      if (tt == 0) {
        aop[dh0] = f2bf(o0[i] * inv);
        aop[32 + dh0] = f2bf(o1[i] * inv);
      } else {
        aop[dh0] = f2bf(o2[i] * inv);
        aop[32 + dh0] = f2bf(o3[i] * inv);
      }
    }
  }
}

extern "C" void kernel_launch(void* const* d_in, const int* in_sizes, int n_in,
                              void* d_out, int out_size, void* d_ws, size_t ws_size,
                              hipStream_t stream) {
  const float* x = (const float*)d_in[0];
  const float* Wq = (const float*)d_in[1];
  const float* bq = (const float*)d_in[2];
  const float* Wk = (const float*)d_in[3];
  const float* bk = (const float*)d_in[4];
  const float* Wv = (const float*)d_in[5];
  const float* bv = (const float*)d_in[6];
  const float* g1 = (const float*)d_in[7];
  const float* be1 = (const float*)d_in[8];
  const float* g2 = (const float*)d_in[9];
  const float* be2 = (const float*)d_in[10];
  const float* W1 = (const float*)d_in[11];
  const float* bf1 = (const float*)d_in[12];
  const float* W2 = (const float*)d_in[13];
  const float* bf2v = (const float*)d_in[14];
  float* out = (float*)d_out;

  char* w = (char*)d_ws;
  size_t off = 0;
  auto alloc = [&](size_t bytes) -> void* {
    void* p = w + off;
    off += (bytes + 255) & ~(size_t)255;
    return p;
  };
  u16* xn_res = (u16*)alloc(16384ull * 512 * 2);
  u16* qbuf = (u16*)alloc(128ull * 1024 * 64 * 2);
  u16* kbuf = (u16*)alloc(128ull * 1024 * 64 * 2);
  u16* vtb = (u16*)alloc(128ull * 64 * 1024 * 2);
  u16* qtb = (u16*)alloc(128ull * 64 * 1024 * 2);
  u16* ktb = (u16*)alloc(128ull * 64 * 1024 * 2);
  u16* wqkv_t = (u16*)alloc(1536ull * 512 * 2);
  u16* w1t = (u16*)alloc(1024ull * 512 * 2);
  u16* w2t = (u16*)alloc(512ull * 1024 * 2);
  u16* h_bf = (u16*)alloc(16384ull * 1024 * 2);
  float* stats = (float*)alloc(128ull * 4 * 4);
  u16* ao_bf = (u16*)alloc(16384ull * 512 * 2);
  u16* xt_bf = (u16*)alloc(16384ull * 512 * 2);

  k_prep_ln1<<<448 + 4096, 256, 0, stream>>>(Wq, Wk, Wv, W1, W2, x, g1, be1,
                                             wqkv_t, w1t, w2t, xn_res);

  k_gemm<0, 128, 12><<<1536, 256, 0, stream>>>(
      xn_res, wqkv_t, 512, 192, bq, bk, bv, qbuf, kbuf, vtb, qtb, ktb, nullptr,
      nullptr);

  k_gram2<<<dim3(128, 2), 256, 0, stream>>>(qtb, ktb, stats);

  k_attn<<<dim3(128, 4), 256, 0, stream>>>(qbuf, kbuf, vtb, stats, ao_bf);

  k_ln2<<<4096, 256, 0, stream>>>(xn_res, ao_bf, g2, be2, xt_bf);

  k_gemm<1, 128, 8><<<1024, 256, 0, stream>>>(
      xt_bf, w1t, 512, 128, bf1, nullptr, nullptr, h_bf, nullptr, nullptr,
      nullptr, nullptr, nullptr, nullptr);
  k_gemm<2, 64, 4><<<1024, 256, 0, stream>>>(
      h_bf, w2t, 1024, 128, bf2v, nullptr, nullptr, nullptr, nullptr, nullptr,
      nullptr, nullptr, xt_bf, out);
  (void)in_sizes; (void)n_in; (void)out_size; (void)ws_size;
}